// Round 1
// baseline (1110.426 us; speedup 1.0000x reference)
//
#include <hip/hip_runtime.h>
#include <math.h>

// Problem constants
#define B_    8
#define CIN   512
#define CK    256
#define CV    512
#define CQKV  768           // CK + CV combined conv
#define HW    4096          // 64*64
#define S_    110           // 1 + 9 + 36 + 64
#define EPS   1e-5f

// ---------------------------------------------------------------------------
// Kernel 1: fused conv1x1 (qk + v combined) + BN + ReLU.  fp32 tiled GEMM.
//   out[co, n] = relu(BN( sum_ci W[co,ci] * x[b,ci,n] ))
//   Tile 64x64, K-tile 16, 256 threads, 4x4 accum per thread.
// ---------------------------------------------------------------------------
__global__ __launch_bounds__(256) void conv_qkv_kernel(
    const float* __restrict__ x,
    const float* __restrict__ qk_w, const float* __restrict__ qk_gamma,
    const float* __restrict__ qk_beta, const float* __restrict__ qk_mean,
    const float* __restrict__ qk_var,
    const float* __restrict__ v_w, const float* __restrict__ v_gamma,
    const float* __restrict__ v_beta, const float* __restrict__ v_mean,
    const float* __restrict__ v_var,
    float* __restrict__ qk_out, float* __restrict__ v_out)
{
    __shared__ float As[16][68];   // [k][m], padded: 272B row stride, 16B aligned
    __shared__ float Bs[16][64];   // [k][n]

    const int b  = blockIdx.z;
    const int m0 = blockIdx.y * 64;      // combined output-channel base (0..704)
    const int n0 = blockIdx.x * 64;
    const int tid = threadIdx.x;
    const int kk = tid & 15, mr = tid >> 4;   // A-load mapping
    const int nn = tid & 63, kr = tid >> 6;   // B-load mapping
    const int tx = tid & 15, ty = tid >> 4;   // compute mapping

    float acc[4][4] = {};
    const float* xb = x + (size_t)b * CIN * HW;

    for (int k0 = 0; k0 < CIN; k0 += 16) {
        #pragma unroll
        for (int q = 0; q < 4; ++q) {
            int row = m0 + mr + 16 * q;
            float w = (row < CK) ? qk_w[row * CIN + k0 + kk]
                                 : v_w[(row - CK) * CIN + k0 + kk];
            As[kk][mr + 16 * q] = w;
        }
        #pragma unroll
        for (int q = 0; q < 4; ++q) {
            int k = kr + 4 * q;
            Bs[k][nn] = xb[(size_t)(k0 + k) * HW + n0 + nn];
        }
        __syncthreads();
        #pragma unroll
        for (int k = 0; k < 16; ++k) {
            float a[4], bb[4];
            #pragma unroll
            for (int i = 0; i < 4; ++i) a[i] = As[k][ty * 4 + i];
            #pragma unroll
            for (int j = 0; j < 4; ++j) bb[j] = Bs[k][tx * 4 + j];
            #pragma unroll
            for (int i = 0; i < 4; ++i)
                #pragma unroll
                for (int j = 0; j < 4; ++j)
                    acc[i][j] = fmaf(a[i], bb[j], acc[i][j]);
        }
        __syncthreads();
    }

    // epilogue: BN + ReLU, route to qk_out or v_out
    #pragma unroll
    for (int i = 0; i < 4; ++i) {
        int row = m0 + ty * 4 + i;
        float sc, sh;
        float* dst;
        if (row < CK) {
            sc = qk_gamma[row] * rsqrtf(qk_var[row] + EPS);
            sh = qk_beta[row] - qk_mean[row] * sc;
            dst = qk_out + ((size_t)b * CK + row) * HW;
        } else {
            int cv = row - CK;
            sc = v_gamma[cv] * rsqrtf(v_var[cv] + EPS);
            sh = v_beta[cv] - v_mean[cv] * sc;
            dst = v_out + ((size_t)b * CV + cv) * HW;
        }
        #pragma unroll
        for (int j = 0; j < 4; ++j) {
            float v = fmaxf(acc[i][j] * sc + sh, 0.0f);
            dst[n0 + tx * 4 + j] = v;
        }
    }
}

// ---------------------------------------------------------------------------
// Kernel 2: PSP adaptive max-pool (sizes 1,3,6,8 -> 110 cells).
//   One block per (channel, batch). Plane staged in LDS, wave per cell.
//   c < CK  -> key[b][c][sc]          (query_key branch)
//   c >= CK -> value[b][sc][c-CK]     (value branch, stored transposed)
// ---------------------------------------------------------------------------
__global__ __launch_bounds__(256) void psp_pool_kernel(
    const float* __restrict__ qk, const float* __restrict__ val,
    float* __restrict__ key, float* __restrict__ value)
{
    __shared__ float plane[HW];
    const int c = blockIdx.x;     // 0..767
    const int b = blockIdx.y;
    const int tid = threadIdx.x;

    const float* src = (c < CK) ? qk + ((size_t)b * CK + c) * HW
                                : val + ((size_t)b * CV + (c - CK)) * HW;
    for (int i = tid; i < HW; i += 256) plane[i] = src[i];
    __syncthreads();

    const int w = tid >> 6, lane = tid & 63;
    for (int sc = w; sc < S_; sc += 4) {
        int s, loc;
        if (sc == 0)      { s = 1; loc = 0; }
        else if (sc < 10) { s = 3; loc = sc - 1; }
        else if (sc < 46) { s = 6; loc = sc - 10; }
        else              { s = 8; loc = sc - 46; }
        int i = loc / s, j = loc - (loc / s) * s;
        int h0 = (i * 64) / s,       h1 = ((i + 1) * 64 + s - 1) / s;
        int w0 = (j * 64) / s,       w1 = ((j + 1) * 64 + s - 1) / s;
        float m = -1e30f;
        for (int h = h0; h < h1; ++h)
            for (int ww = w0 + lane; ww < w1; ww += 64)
                m = fmaxf(m, plane[h * 64 + ww]);
        #pragma unroll
        for (int off = 32; off; off >>= 1) m = fmaxf(m, __shfl_xor(m, off));
        if (lane == 0) {
            if (c < CK) key[((size_t)b * CK + c) * S_ + sc] = m;
            else        value[((size_t)b * S_ + sc) * CV + (c - CK)] = m;
        }
    }
}

// ---------------------------------------------------------------------------
// Kernel 3: scores = softmax( (Q @ K) * 1/16 ) fused.
//   Block = 64 n-rows x all 110 s for one batch. Wave g owns s-range
//   [g*28, min((g+1)*28, 110)), lane = n row.
// ---------------------------------------------------------------------------
__global__ __launch_bounds__(256) void attn_scores_kernel(
    const float* __restrict__ qk, const float* __restrict__ key,
    float* __restrict__ P)
{
    __shared__ float Aq[64][64];     // [c][n]
    __shared__ float Ks[64][112];    // [c][s], padded to 112 (448B rows)
    __shared__ float red[4][64];

    const int b  = blockIdx.y;
    const int n0 = blockIdx.x * 64;
    const int tid = threadIdx.x;
    const int nl = tid & 63, g = tid >> 6;
    const int smax = (g == 3) ? 26 : 28;

    float acc[28];
    #pragma unroll
    for (int q = 0; q < 28; ++q) acc[q] = 0.f;

    for (int c0 = 0; c0 < CK; c0 += 64) {
        #pragma unroll
        for (int q = 0; q < 16; ++q) {
            int cc = g + 4 * q;
            Aq[cc][nl] = qk[((size_t)b * CK + c0 + cc) * HW + n0 + nl];
        }
        for (int idx = tid; idx < 64 * S_; idx += 256) {
            int cc = idx / S_, s = idx - cc * S_;
            Ks[cc][s] = key[((size_t)b * CK + c0 + cc) * S_ + s];
        }
        // zero the 2 pad columns so stray reads can't poison (unused) acc slots
        for (int idx = tid; idx < 128; idx += 256)
            Ks[idx >> 1][S_ + (idx & 1)] = 0.f;
        __syncthreads();
        for (int cc = 0; cc < 64; ++cc) {
            float qv = Aq[cc][nl];
            #pragma unroll
            for (int q = 0; q < 28; ++q)
                acc[q] = fmaf(qv, Ks[cc][g * 28 + q], acc[q]);
        }
        __syncthreads();
    }

    // scale + softmax over s (cross-wave via LDS)
    float mloc = -1e30f;
    for (int q = 0; q < smax; ++q) { acc[q] *= 0.0625f; mloc = fmaxf(mloc, acc[q]); }
    red[g][nl] = mloc;
    __syncthreads();
    float rmax = fmaxf(fmaxf(red[0][nl], red[1][nl]), fmaxf(red[2][nl], red[3][nl]));
    __syncthreads();
    float sloc = 0.f;
    for (int q = 0; q < smax; ++q) { float e = __expf(acc[q] - rmax); acc[q] = e; sloc += e; }
    red[g][nl] = sloc;
    __syncthreads();
    float rsum = red[0][nl] + red[1][nl] + red[2][nl] + red[3][nl];
    float inv = 1.f / rsum;
    float* Prow = P + ((size_t)b * HW + n0 + nl) * S_ + g * 28;
    for (int q = 0; q < smax; ++q) Prow[q] = acc[q] * inv;
}

// ---------------------------------------------------------------------------
// Kernel 4: Y[b][cv][n] = sum_s P[b][n][s] * value[b][s][cv]  (PV GEMM)
//   Tile 64 cv x 64 n, full K=110 in LDS. 256 threads, 4x4 accum.
// ---------------------------------------------------------------------------
__global__ __launch_bounds__(256) void attn_pv_kernel(
    const float* __restrict__ P, const float* __restrict__ value,
    float* __restrict__ Y)
{
    __shared__ float Vs[S_][64];   // [s][cv]
    __shared__ float Pt[S_][64];   // [s][n]

    const int b = blockIdx.z, cv0 = blockIdx.y * 64, n0 = blockIdx.x * 64;
    const int tid = threadIdx.x;
    const int nn = tid & 63, sr = tid >> 6;
    const int tx = tid & 15, ty = tid >> 4;

    for (int s = sr; s < S_; s += 4)
        Vs[s][nn] = value[((size_t)b * S_ + s) * CV + cv0 + nn];
    for (int s = sr; s < S_; s += 4)
        Pt[s][nn] = P[((size_t)b * HW + n0 + nn) * S_ + s];
    __syncthreads();

    float acc[4][4] = {};
    for (int s = 0; s < S_; ++s) {
        float a[4], pb[4];
        #pragma unroll
        for (int i = 0; i < 4; ++i) a[i] = Vs[s][ty * 4 + i];
        #pragma unroll
        for (int j = 0; j < 4; ++j) pb[j] = Pt[s][tx * 4 + j];
        #pragma unroll
        for (int i = 0; i < 4; ++i)
            #pragma unroll
            for (int j = 0; j < 4; ++j)
                acc[i][j] = fmaf(a[i], pb[j], acc[i][j]);
    }
    #pragma unroll
    for (int i = 0; i < 4; ++i)
        #pragma unroll
        for (int j = 0; j < 4; ++j)
            Y[((size_t)b * CV + cv0 + ty * 4 + i) * HW + n0 + tx * 4 + j] = acc[i][j];
}

// ---------------------------------------------------------------------------
// Kernel 5: out = BN(conv1x1(Y, out_w)) + x   (no activation)
// ---------------------------------------------------------------------------
__global__ __launch_bounds__(256) void conv_out_kernel(
    const float* __restrict__ Y, const float* __restrict__ out_w,
    const float* __restrict__ gamma, const float* __restrict__ beta,
    const float* __restrict__ mean, const float* __restrict__ var,
    const float* __restrict__ x, float* __restrict__ out)
{
    __shared__ float As[16][68];
    __shared__ float Bs[16][64];

    const int b  = blockIdx.z;
    const int m0 = blockIdx.y * 64;   // 0..448 (Cin=512)
    const int n0 = blockIdx.x * 64;
    const int tid = threadIdx.x;
    const int kk = tid & 15, mr = tid >> 4;
    const int nn = tid & 63, kr = tid >> 6;
    const int tx = tid & 15, ty = tid >> 4;

    float acc[4][4] = {};
    const float* Yb = Y + (size_t)b * CV * HW;

    for (int k0 = 0; k0 < CV; k0 += 16) {
        #pragma unroll
        for (int q = 0; q < 4; ++q)
            As[kk][mr + 16 * q] = out_w[(m0 + mr + 16 * q) * CV + k0 + kk];
        #pragma unroll
        for (int q = 0; q < 4; ++q) {
            int k = kr + 4 * q;
            Bs[k][nn] = Yb[(size_t)(k0 + k) * HW + n0 + nn];
        }
        __syncthreads();
        #pragma unroll
        for (int k = 0; k < 16; ++k) {
            float a[4], bb[4];
            #pragma unroll
            for (int i = 0; i < 4; ++i) a[i] = As[k][ty * 4 + i];
            #pragma unroll
            for (int j = 0; j < 4; ++j) bb[j] = Bs[k][tx * 4 + j];
            #pragma unroll
            for (int i = 0; i < 4; ++i)
                #pragma unroll
                for (int j = 0; j < 4; ++j)
                    acc[i][j] = fmaf(a[i], bb[j], acc[i][j]);
        }
        __syncthreads();
    }

    #pragma unroll
    for (int i = 0; i < 4; ++i) {
        int row = m0 + ty * 4 + i;
        float sc = gamma[row] * rsqrtf(var[row] + EPS);
        float sh = beta[row] - mean[row] * sc;
        const float* xr = x + ((size_t)b * CIN + row) * HW;
        float* orow = out + ((size_t)b * CIN + row) * HW;
        #pragma unroll
        for (int j = 0; j < 4; ++j) {
            int n = n0 + tx * 4 + j;
            orow[n] = acc[i][j] * sc + sh + xr[n];
        }
    }
}

// ---------------------------------------------------------------------------
// Launch
// ---------------------------------------------------------------------------
extern "C" void kernel_launch(void* const* d_in, const int* in_sizes, int n_in,
                              void* d_out, int out_size, void* d_ws, size_t ws_size,
                              hipStream_t stream)
{
    const float* x        = (const float*)d_in[0];
    const float* qk_w     = (const float*)d_in[1];
    const float* qk_gamma = (const float*)d_in[2];
    const float* qk_beta  = (const float*)d_in[3];
    const float* qk_mean  = (const float*)d_in[4];
    const float* qk_var   = (const float*)d_in[5];
    const float* v_w      = (const float*)d_in[6];
    const float* v_gamma  = (const float*)d_in[7];
    const float* v_beta   = (const float*)d_in[8];
    const float* v_mean   = (const float*)d_in[9];
    const float* v_var    = (const float*)d_in[10];
    const float* out_w    = (const float*)d_in[11];
    const float* out_gamma= (const float*)d_in[12];
    const float* out_beta = (const float*)d_in[13];
    const float* out_mean = (const float*)d_in[14];
    const float* out_var  = (const float*)d_in[15];

    float* ws = (float*)d_ws;
    // layout (floats): qk[8.39M] | val/Y[16.78M] | key[225K] | value[450K] | P[3.6M]
    float* qk    = ws;                       // 8*256*4096
    float* val   = ws + 8388608ull;          // 8*512*4096  (reused as Y)
    float* key   = ws + 25165824ull;         // 8*256*110
    float* value = ws + 25391104ull;         // 8*110*512
    float* P     = ws + 25841664ull;         // 8*4096*110

    conv_qkv_kernel<<<dim3(HW / 64, CQKV / 64, B_), 256, 0, stream>>>(
        x, qk_w, qk_gamma, qk_beta, qk_mean, qk_var,
        v_w, v_gamma, v_beta, v_mean, v_var, qk, val);

    psp_pool_kernel<<<dim3(CQKV, B_), 256, 0, stream>>>(qk, val, key, value);

    attn_scores_kernel<<<dim3(HW / 64, B_), 256, 0, stream>>>(qk, key, P);

    attn_pv_kernel<<<dim3(HW / 64, CV / 64, B_), 256, 0, stream>>>(P, value, val /*Y aliases val*/);

    conv_out_kernel<<<dim3(HW / 64, CIN / 64, B_), 256, 0, stream>>>(
        val /*Y*/, out_w, out_gamma, out_beta, out_mean, out_var,
        x, (float*)d_out);
}

// Round 5
// 638.277 us; speedup vs baseline: 1.7397x; 1.7397x over previous
//
#include <hip/hip_runtime.h>
#include <math.h>

#define B_    8
#define CIN   512
#define CK    256
#define CV    512
#define HW    4096
#define S_    110
#define EPS   1e-5f

typedef __attribute__((ext_vector_type(8))) short bf16x8;
typedef __attribute__((ext_vector_type(4))) short bf16x4;
typedef __attribute__((ext_vector_type(4))) float f32x4;

__device__ __forceinline__ float b2f(short s) {
    unsigned int u = ((unsigned int)(unsigned short)s) << 16;
    union { unsigned int u; float f; } c; c.u = u; return c.f;
}
__device__ __forceinline__ short f2b(float f) {
    union { float f; unsigned int u; } c; c.f = f;
    unsigned int r = (c.u + 0x7FFFu + ((c.u >> 16) & 1u)) >> 16;   // RNE
    return (short)r;
}

// ---------------------------------------------------------------------------
// Kernel A: x [b][c][n] fp32 -> xt [b][n][c] bf16  (transpose + convert)
// ---------------------------------------------------------------------------
__global__ __launch_bounds__(256) void transpose_x_kernel(
    const float* __restrict__ x, short* __restrict__ xt)
{
    __shared__ short t[64][65];
    const int b = blockIdx.z, c0 = blockIdx.y * 64, n0 = blockIdx.x * 64;
    const int tid = threadIdx.x;
    const float* src = x + ((size_t)b * CIN + c0) * HW + n0;
    const int j = tid & 63, i0 = tid >> 6;
    #pragma unroll
    for (int q = 0; q < 16; ++q) {
        int i = i0 * 16 + q;
        t[i][j] = f2b(src[(size_t)i * HW + j]);
    }
    __syncthreads();
    short* dst = xt + ((size_t)b * HW + n0) * CIN + c0;
    const int hh = tid & 31, jb = tid >> 5;
    #pragma unroll
    for (int q = 0; q < 8; ++q) {
        int jj = jb * 8 + q;
        short2 v; v.x = t[2 * hh][jj]; v.y = t[2 * hh + 1][jj];
        *(short2*)(dst + (size_t)jj * CIN + 2 * hh) = v;
    }
}

// ---------------------------------------------------------------------------
// Kernel B: convert all three weight matrices to bf16 (contiguous buffer)
//   layout: [0,131072) qk_w | [131072,393216) v_w | [393216,655360) out_w
// ---------------------------------------------------------------------------
__global__ __launch_bounds__(256) void convert_w_kernel(
    const float* __restrict__ qk_w, const float* __restrict__ v_w,
    const float* __restrict__ out_w, short* __restrict__ wb)
{
    const int id4 = (blockIdx.x * 256 + threadIdx.x) * 4;
    #pragma unroll
    for (int r = 0; r < 4; ++r) {
        int id = id4 + r;
        float f = (id < 131072) ? qk_w[id]
                : (id < 393216) ? v_w[id - 131072]
                                : out_w[id - 393216];
        wb[id] = f2b(f);
    }
}

// ---------------------------------------------------------------------------
// MFMA GEMM: C[co][n] = sum_k W[co][k] * Bt[n][k],  bf16 inputs, fp32 acc.
//   128x128 tile, BK=64, 4 waves (2x2), 16x16x32 MFMA, XOR-swizzled LDS.
//   MODE 0: BN+ReLU epilogue, split write to qk (bf16) / val (bf16). M=768.
//   MODE 1: BN + residual(x) epilogue, write fp32 d_out. M=512.
// ---------------------------------------------------------------------------
template<int MODE>
__global__ __launch_bounds__(256) void gemm_mfma_kernel(
    const short* __restrict__ W, const short* __restrict__ Bt,
    const float* __restrict__ g0, const float* __restrict__ be0,
    const float* __restrict__ mu0, const float* __restrict__ va0,
    const float* __restrict__ g1, const float* __restrict__ be1,
    const float* __restrict__ mu1, const float* __restrict__ va1,
    const float* __restrict__ xres,
    short* __restrict__ o0, short* __restrict__ o1,
    float* __restrict__ of)
{
    __shared__ short As[128 * 64];
    __shared__ short Bs[128 * 64];
    const int b   = blockIdx.z;
    const int mm0 = blockIdx.y * 128, nn0 = blockIdx.x * 128;
    const int tid = threadIdx.x;
    const int lane = tid & 63, wv = tid >> 6;
    const int wm = (wv >> 1) * 64, wn = (wv & 1) * 64;
    const int l15 = lane & 15, l4 = lane >> 4;

    // staging mapping: 2 threads per row, each thread 4x 16B units
    const int srow = tid >> 1, shalf = tid & 1;
    const short* wsrc = W + (size_t)(mm0 + srow) * 512 + shalf * 32;
    const short* xsrc = Bt + ((size_t)b * HW + nn0 + srow) * 512 + shalf * 32;
    int woff[4];
    #pragma unroll
    for (int q = 0; q < 4; ++q) {
        int unit = shalf * 4 + q;
        woff[q] = srow * 64 + (unit ^ (srow & 7)) * 8;
    }

    f32x4 acc[4][4] = {};

    for (int kt = 0; kt < 512; kt += 64) {
        #pragma unroll
        for (int q = 0; q < 4; ++q)
            *(bf16x8*)&As[woff[q]] = *(const bf16x8*)(wsrc + kt + q * 8);
        #pragma unroll
        for (int q = 0; q < 4; ++q)
            *(bf16x8*)&Bs[woff[q]] = *(const bf16x8*)(xsrc + kt + q * 8);
        __syncthreads();
        #pragma unroll
        for (int kk = 0; kk < 2; ++kk) {
            bf16x8 af[4], bfr[4];
            #pragma unroll
            for (int m = 0; m < 4; ++m) {
                int row = wm + m * 16 + l15;
                int su = (kk * 4 + l4) ^ (row & 7);
                af[m] = *(const bf16x8*)&As[row * 64 + su * 8];
            }
            #pragma unroll
            for (int n = 0; n < 4; ++n) {
                int row = wn + n * 16 + l15;
                int su = (kk * 4 + l4) ^ (row & 7);
                bfr[n] = *(const bf16x8*)&Bs[row * 64 + su * 8];
            }
            #pragma unroll
            for (int m = 0; m < 4; ++m)
                #pragma unroll
                for (int n = 0; n < 4; ++n)
                    acc[m][n] = __builtin_amdgcn_mfma_f32_16x16x32_bf16(
                        af[m], bfr[n], acc[m][n], 0, 0, 0);
        }
        __syncthreads();
    }

    // epilogue: D[row = m*16 + 4*l4 + i][col = n*16 + l15]
    #pragma unroll
    for (int m = 0; m < 4; ++m) {
        #pragma unroll
        for (int i = 0; i < 4; ++i) {
            const int co = mm0 + wm + m * 16 + l4 * 4 + i;
            if (MODE == 0) {
                float sc, sh; short* dst;
                if (co < CK) {
                    sc = g0[co] * rsqrtf(va0[co] + EPS);
                    sh = be0[co] - mu0[co] * sc;
                    dst = o0 + ((size_t)b * CK + co) * HW;
                } else {
                    int cv = co - CK;
                    sc = g1[cv] * rsqrtf(va1[cv] + EPS);
                    sh = be1[cv] - mu1[cv] * sc;
                    dst = o1 + ((size_t)b * CV + cv) * HW;
                }
                #pragma unroll
                for (int n = 0; n < 4; ++n) {
                    float v = fmaxf(acc[m][n][i] * sc + sh, 0.f);
                    dst[nn0 + wn + n * 16 + l15] = f2b(v);
                }
            } else {
                float sc = g0[co] * rsqrtf(va0[co] + EPS);
                float sh = be0[co] - mu0[co] * sc;
                const float* xr = xres + ((size_t)b * CIN + co) * HW;
                float* orow = of + ((size_t)b * CIN + co) * HW;
                #pragma unroll
                for (int n = 0; n < 4; ++n) {
                    int nidx = nn0 + wn + n * 16 + l15;
                    orow[nidx] = acc[m][n][i] * sc + sh + xr[nidx];
                }
            }
        }
    }
}

// ---------------------------------------------------------------------------
// Kernel: PSP adaptive max-pool (bf16 inputs).
// ---------------------------------------------------------------------------
__global__ __launch_bounds__(256) void psp_pool_kernel(
    const short* __restrict__ qkb, const short* __restrict__ valb,
    float* __restrict__ key, float* __restrict__ value)
{
    __shared__ float plane[HW];
    const int c = blockIdx.x, b = blockIdx.y;
    const int tid = threadIdx.x;
    const short* src = (c < CK) ? qkb + ((size_t)b * CK + c) * HW
                                : valb + ((size_t)b * CV + (c - CK)) * HW;
    #pragma unroll
    for (int q = 0; q < 2; ++q) {
        bf16x8 v = *(const bf16x8*)(src + tid * 16 + q * 8);
        #pragma unroll
        for (int e = 0; e < 8; ++e) plane[tid * 16 + q * 8 + e] = b2f(v[e]);
    }
    __syncthreads();

    const int w = tid >> 6, lane = tid & 63;
    for (int sc = w; sc < S_; sc += 4) {
        int s, loc;
        if (sc == 0)      { s = 1; loc = 0; }
        else if (sc < 10) { s = 3; loc = sc - 1; }
        else if (sc < 46) { s = 6; loc = sc - 10; }
        else              { s = 8; loc = sc - 46; }
        int i = loc / s, j = loc - (loc / s) * s;
        int h0 = (i * 64) / s, h1 = ((i + 1) * 64 + s - 1) / s;
        int w0 = (j * 64) / s, w1 = ((j + 1) * 64 + s - 1) / s;
        float m = -1e30f;
        for (int h = h0; h < h1; ++h)
            for (int ww = w0 + lane; ww < w1; ww += 64)
                m = fmaxf(m, plane[h * 64 + ww]);
        #pragma unroll
        for (int off = 32; off; off >>= 1) m = fmaxf(m, __shfl_xor(m, off));
        if (lane == 0) {
            if (c < CK) key[((size_t)b * CK + c) * S_ + sc] = m;
            else        value[((size_t)b * S_ + sc) * CV + (c - CK)] = m;
        }
    }
}

// ---------------------------------------------------------------------------
// Kernel: scores = softmax((Q@K)/16), fp32 compute, bf16 Q input.
// ---------------------------------------------------------------------------
__global__ __launch_bounds__(256) void attn_scores_kernel(
    const short* __restrict__ qkb, const float* __restrict__ key,
    float* __restrict__ P)
{
    __shared__ float Aq[64][64];
    __shared__ float Ks[64][112];
    __shared__ float red[4][64];

    const int b  = blockIdx.y;
    const int n0 = blockIdx.x * 64;
    const int tid = threadIdx.x;
    const int nl = tid & 63, g = tid >> 6;
    const int smax = (g == 3) ? 26 : 28;

    float acc[28];
    #pragma unroll
    for (int q = 0; q < 28; ++q) acc[q] = 0.f;

    for (int c0 = 0; c0 < CK; c0 += 64) {
        #pragma unroll
        for (int q = 0; q < 16; ++q) {
            int cc = g + 4 * q;
            Aq[cc][nl] = b2f(qkb[((size_t)b * CK + c0 + cc) * HW + n0 + nl]);
        }
        for (int idx = tid; idx < 64 * S_; idx += 256) {
            int cc = idx / S_, s = idx - cc * S_;
            Ks[cc][s] = key[((size_t)b * CK + c0 + cc) * S_ + s];
        }
        for (int idx = tid; idx < 128; idx += 256)
            Ks[idx >> 1][S_ + (idx & 1)] = 0.f;
        __syncthreads();
        for (int cc = 0; cc < 64; ++cc) {
            float qv = Aq[cc][nl];
            #pragma unroll
            for (int q = 0; q < 28; ++q)
                acc[q] = fmaf(qv, Ks[cc][g * 28 + q], acc[q]);
        }
        __syncthreads();
    }

    float mloc = -1e30f;
    for (int q = 0; q < smax; ++q) { acc[q] *= 0.0625f; mloc = fmaxf(mloc, acc[q]); }
    red[g][nl] = mloc;
    __syncthreads();
    float rmax = fmaxf(fmaxf(red[0][nl], red[1][nl]), fmaxf(red[2][nl], red[3][nl]));
    __syncthreads();
    float sloc = 0.f;
    for (int q = 0; q < smax; ++q) { float e = __expf(acc[q] - rmax); acc[q] = e; sloc += e; }
    red[g][nl] = sloc;
    __syncthreads();
    float rsum = red[0][nl] + red[1][nl] + red[2][nl] + red[3][nl];
    float inv = 1.f / rsum;
    float* Prow = P + ((size_t)b * HW + n0 + nl) * S_ + g * 28;
    for (int q = 0; q < smax; ++q) Prow[q] = acc[q] * inv;
}

// ---------------------------------------------------------------------------
// Kernel: Yt[b][n][cv] (bf16) = sum_s P[b][n][s] * value[b][s][cv]
//   fp32 compute; output written transposed (n-major) for the out-conv MFMA.
// ---------------------------------------------------------------------------
__global__ __launch_bounds__(256) void attn_pv_kernel(
    const float* __restrict__ P, const float* __restrict__ value,
    short* __restrict__ Yt)
{
    __shared__ float Vs[S_][64];
    __shared__ float Pt[S_][64];

    const int b = blockIdx.z, cv0 = blockIdx.y * 64, n0 = blockIdx.x * 64;
    const int tid = threadIdx.x;
    const int nn = tid & 63, sr = tid >> 6;
    const int tx = tid & 15, ty = tid >> 4;   // tx -> cv, ty -> n

    for (int s = sr; s < S_; s += 4)
        Vs[s][nn] = value[((size_t)b * S_ + s) * CV + cv0 + nn];
    for (int s = sr; s < S_; s += 4)
        Pt[s][nn] = P[((size_t)b * HW + n0 + nn) * S_ + s];
    __syncthreads();

    float acc[4][4] = {};  // [i: n][j: cv]
    for (int s = 0; s < S_; ++s) {
        float a[4], vv[4];
        #pragma unroll
        for (int i = 0; i < 4; ++i) a[i] = Pt[s][ty * 4 + i];
        #pragma unroll
        for (int j = 0; j < 4; ++j) vv[j] = Vs[s][tx * 4 + j];
        #pragma unroll
        for (int i = 0; i < 4; ++i)
            #pragma unroll
            for (int j = 0; j < 4; ++j)
                acc[i][j] = fmaf(a[i], vv[j], acc[i][j]);
    }
    #pragma unroll
    for (int i = 0; i < 4; ++i) {
        short* dst = Yt + ((size_t)b * HW + n0 + ty * 4 + i) * CV + cv0 + tx * 4;
        bf16x4 v;
        #pragma unroll
        for (int j = 0; j < 4; ++j) v[j] = f2b(acc[i][j]);
        *(bf16x4*)dst = v;
    }
}

// ---------------------------------------------------------------------------
// Launch
// ---------------------------------------------------------------------------
extern "C" void kernel_launch(void* const* d_in, const int* in_sizes, int n_in,
                              void* d_out, int out_size, void* d_ws, size_t ws_size,
                              hipStream_t stream)
{
    const float* x        = (const float*)d_in[0];
    const float* qk_w     = (const float*)d_in[1];
    const float* qk_gamma = (const float*)d_in[2];
    const float* qk_beta  = (const float*)d_in[3];
    const float* qk_mean  = (const float*)d_in[4];
    const float* qk_var   = (const float*)d_in[5];
    const float* v_w      = (const float*)d_in[6];
    const float* v_gamma  = (const float*)d_in[7];
    const float* v_beta   = (const float*)d_in[8];
    const float* v_mean   = (const float*)d_in[9];
    const float* v_var    = (const float*)d_in[10];
    const float* out_w    = (const float*)d_in[11];
    const float* out_gamma= (const float*)d_in[12];
    const float* out_beta = (const float*)d_in[13];
    const float* out_mean = (const float*)d_in[14];
    const float* out_var  = (const float*)d_in[15];

    char* wsb = (char*)d_ws;
    short* xt    = (short*)(wsb);                 // [8][4096][512] bf16  33.5 MB
    short* qkb   = (short*)(wsb + 33554432);      // [8][256][4096] bf16  16.8 MB
    short* valb  = (short*)(wsb + 50331648);      // [8][512][4096] bf16  33.5 MB
    short* Yt    = valb;                          // [8][4096][512] bf16 (aliases valb; valb dead after pool)
    float* key   = (float*)(wsb + 83886080);      // [8][256][110]
    float* value = (float*)(wsb + 84787200);      // [8][110][512]
    float* P     = (float*)(wsb + 86589440);      // [8][4096][110]
    short* wqkv  = (short*)(wsb + 101007360);     // [768][512]
    short* wout  = wqkv + 393216;                 // [512][512]

    transpose_x_kernel<<<dim3(HW / 64, CIN / 64, B_), 256, 0, stream>>>(x, xt);
    convert_w_kernel<<<dim3(640), 256, 0, stream>>>(qk_w, v_w, out_w, wqkv);

    gemm_mfma_kernel<0><<<dim3(HW / 128, 6, B_), 256, 0, stream>>>(
        wqkv, xt, qk_gamma, qk_beta, qk_mean, qk_var,
        v_gamma, v_beta, v_mean, v_var,
        nullptr, qkb, valb, nullptr);

    psp_pool_kernel<<<dim3(CK + CV, B_), 256, 0, stream>>>(qkb, valb, key, value);

    attn_scores_kernel<<<dim3(HW / 64, B_), 256, 0, stream>>>(qkb, key, P);

    attn_pv_kernel<<<dim3(HW / 64, CV / 64, B_), 256, 0, stream>>>(P, value, Yt);

    gemm_mfma_kernel<1><<<dim3(HW / 128, 4, B_), 256, 0, stream>>>(
        wout, Yt, out_gamma, out_beta, out_mean, out_var,
        nullptr, nullptr, nullptr, nullptr,
        x, nullptr, nullptr, (float*)d_out);
}

// Round 6
// 390.175 us; speedup vs baseline: 2.8460x; 1.6359x over previous
//
#include <hip/hip_runtime.h>
#include <math.h>

#define B_    8
#define CIN   512
#define CK    256
#define CV    512
#define HW    4096
#define S_    110
#define EPS   1e-5f

typedef __attribute__((ext_vector_type(8))) short bf16x8;
typedef __attribute__((ext_vector_type(4))) short bf16x4;
typedef __attribute__((ext_vector_type(4))) float f32x4;

__device__ __forceinline__ float b2f(short s) {
    unsigned int u = ((unsigned int)(unsigned short)s) << 16;
    union { unsigned int u; float f; } c; c.u = u; return c.f;
}
__device__ __forceinline__ short f2b(float f) {
    union { float f; unsigned int u; } c; c.f = f;
    unsigned int r = (c.u + 0x7FFFu + ((c.u >> 16) & 1u)) >> 16;   // RNE
    return (short)r;
}

// ---------------------------------------------------------------------------
// Kernel A: x [b][c][n] fp32 -> xt [b][n][c] bf16  (transpose + convert)
// ---------------------------------------------------------------------------
__global__ __launch_bounds__(256) void transpose_x_kernel(
    const float* __restrict__ x, short* __restrict__ xt)
{
    __shared__ short t[64][65];
    const int b = blockIdx.z, c0 = blockIdx.y * 64, n0 = blockIdx.x * 64;
    const int tid = threadIdx.x;
    const float* src = x + ((size_t)b * CIN + c0) * HW + n0;
    const int j = tid & 63, i0 = tid >> 6;
    #pragma unroll
    for (int q = 0; q < 16; ++q) {
        int i = i0 * 16 + q;
        t[i][j] = f2b(src[(size_t)i * HW + j]);
    }
    __syncthreads();
    short* dst = xt + ((size_t)b * HW + n0) * CIN + c0;
    const int hh = tid & 31, jb = tid >> 5;
    #pragma unroll
    for (int q = 0; q < 8; ++q) {
        int jj = jb * 8 + q;
        short2 v; v.x = t[2 * hh][jj]; v.y = t[2 * hh + 1][jj];
        *(short2*)(dst + (size_t)jj * CIN + 2 * hh) = v;
    }
}

// ---------------------------------------------------------------------------
// Kernel B: convert all three weight matrices to bf16 (contiguous buffer)
// ---------------------------------------------------------------------------
__global__ __launch_bounds__(256) void convert_w_kernel(
    const float* __restrict__ qk_w, const float* __restrict__ v_w,
    const float* __restrict__ out_w, short* __restrict__ wb)
{
    const int id4 = (blockIdx.x * 256 + threadIdx.x) * 4;
    #pragma unroll
    for (int r = 0; r < 4; ++r) {
        int id = id4 + r;
        float f = (id < 131072) ? qk_w[id]
                : (id < 393216) ? v_w[id - 131072]
                                : out_w[id - 393216];
        wb[id] = f2b(f);
    }
}

// ---------------------------------------------------------------------------
// MFMA GEMM: C[co][n] = sum_k W[co][k] * Bt[n][k],  bf16 inputs, fp32 acc.
//   128x128 tile, BK=64, 4 waves (2x2), 16x16x32 MFMA, XOR-swizzled LDS.
//   MODE 0: BN+ReLU epilogue, split write to qk (bf16) / val (bf16). M=768.
//   MODE 1: BN + residual(x) epilogue, write fp32 d_out. M=512.
// ---------------------------------------------------------------------------
template<int MODE>
__global__ __launch_bounds__(256) void gemm_mfma_kernel(
    const short* __restrict__ W, const short* __restrict__ Bt,
    const float* __restrict__ g0, const float* __restrict__ be0,
    const float* __restrict__ mu0, const float* __restrict__ va0,
    const float* __restrict__ g1, const float* __restrict__ be1,
    const float* __restrict__ mu1, const float* __restrict__ va1,
    const float* __restrict__ xres,
    short* __restrict__ o0, short* __restrict__ o1,
    float* __restrict__ of)
{
    __shared__ short As[128 * 64];
    __shared__ short Bs[128 * 64];
    const int b   = blockIdx.z;
    const int mm0 = blockIdx.y * 128, nn0 = blockIdx.x * 128;
    const int tid = threadIdx.x;
    const int lane = tid & 63, wv = tid >> 6;
    const int wm = (wv >> 1) * 64, wn = (wv & 1) * 64;
    const int l15 = lane & 15, l4 = lane >> 4;

    const int srow = tid >> 1, shalf = tid & 1;
    const short* wsrc = W + (size_t)(mm0 + srow) * 512 + shalf * 32;
    const short* xsrc = Bt + ((size_t)b * HW + nn0 + srow) * 512 + shalf * 32;
    int woff[4];
    #pragma unroll
    for (int q = 0; q < 4; ++q) {
        int unit = shalf * 4 + q;
        woff[q] = srow * 64 + (unit ^ (srow & 7)) * 8;
    }

    f32x4 acc[4][4] = {};

    for (int kt = 0; kt < 512; kt += 64) {
        #pragma unroll
        for (int q = 0; q < 4; ++q)
            *(bf16x8*)&As[woff[q]] = *(const bf16x8*)(wsrc + kt + q * 8);
        #pragma unroll
        for (int q = 0; q < 4; ++q)
            *(bf16x8*)&Bs[woff[q]] = *(const bf16x8*)(xsrc + kt + q * 8);
        __syncthreads();
        #pragma unroll
        for (int kk = 0; kk < 2; ++kk) {
            bf16x8 af[4], bfr[4];
            #pragma unroll
            for (int m = 0; m < 4; ++m) {
                int row = wm + m * 16 + l15;
                int su = (kk * 4 + l4) ^ (row & 7);
                af[m] = *(const bf16x8*)&As[row * 64 + su * 8];
            }
            #pragma unroll
            for (int n = 0; n < 4; ++n) {
                int row = wn + n * 16 + l15;
                int su = (kk * 4 + l4) ^ (row & 7);
                bfr[n] = *(const bf16x8*)&Bs[row * 64 + su * 8];
            }
            #pragma unroll
            for (int m = 0; m < 4; ++m)
                #pragma unroll
                for (int n = 0; n < 4; ++n)
                    acc[m][n] = __builtin_amdgcn_mfma_f32_16x16x32_bf16(
                        af[m], bfr[n], acc[m][n], 0, 0, 0);
        }
        __syncthreads();
    }

    #pragma unroll
    for (int m = 0; m < 4; ++m) {
        #pragma unroll
        for (int i = 0; i < 4; ++i) {
            const int co = mm0 + wm + m * 16 + l4 * 4 + i;
            if (MODE == 0) {
                float sc, sh; short* dst;
                if (co < CK) {
                    sc = g0[co] * rsqrtf(va0[co] + EPS);
                    sh = be0[co] - mu0[co] * sc;
                    dst = o0 + ((size_t)b * CK + co) * HW;
                } else {
                    int cv = co - CK;
                    sc = g1[cv] * rsqrtf(va1[cv] + EPS);
                    sh = be1[cv] - mu1[cv] * sc;
                    dst = o1 + ((size_t)b * CV + cv) * HW;
                }
                #pragma unroll
                for (int n = 0; n < 4; ++n) {
                    float v = fmaxf(acc[m][n][i] * sc + sh, 0.f);
                    dst[nn0 + wn + n * 16 + l15] = f2b(v);
                }
            } else {
                float sc = g0[co] * rsqrtf(va0[co] + EPS);
                float sh = be0[co] - mu0[co] * sc;
                const float* xr = xres + ((size_t)b * CIN + co) * HW;
                float* orow = of + ((size_t)b * CIN + co) * HW;
                #pragma unroll
                for (int n = 0; n < 4; ++n) {
                    int nidx = nn0 + wn + n * 16 + l15;
                    orow[nidx] = acc[m][n][i] * sc + sh + xr[nidx];
                }
            }
        }
    }
}

// ---------------------------------------------------------------------------
// Kernel: PSP adaptive max-pool — separable, wave-per-plane.
//   Lane = column. Phase 1: stream 64 rows, keep 17 h-band maxima in regs
//   (membership compile-time via full unroll; no divides, no divergence).
//   Phase 2: bands -> LDS, one cell per lane with literal-divisor bounds.
//   Band rows: 0-2 = s3 h-bands, 3-8 = s6, 9-16 = s8. s=1 via butterfly.
// ---------------------------------------------------------------------------
__global__ __launch_bounds__(256) void psp_pool_kernel(
    const short* __restrict__ qkb, const short* __restrict__ valb,
    float* __restrict__ key, float* __restrict__ value)
{
    __shared__ float band[4][17][64];
    const int tid = threadIdx.x;
    const int lane = tid & 63, wv = tid >> 6;
    const int c = blockIdx.x * 4 + wv;
    const int b = blockIdx.y;

    const short* src = (c < CK) ? qkb + ((size_t)b * CK + c) * HW
                                : valb + ((size_t)b * CV + (c - CK)) * HW;

    const float NEG = -1e30f;
    float a0 = NEG;
    float b3[3] = {NEG, NEG, NEG};
    float c6[6] = {NEG, NEG, NEG, NEG, NEG, NEG};
    float d8[8] = {NEG, NEG, NEG, NEG, NEG, NEG, NEG, NEG};

    #pragma unroll
    for (int h = 0; h < 64; ++h) {
        float v = b2f(src[h * 64 + lane]);
        a0 = fmaxf(a0, v);
        // s=3 h-bands: [0,22) [21,43) [42,64)
        if (h <= 21)            b3[0] = fmaxf(b3[0], v);
        if (h >= 21 && h <= 42) b3[1] = fmaxf(b3[1], v);
        if (h >= 42)            b3[2] = fmaxf(b3[2], v);
        // s=6 h-bands: [0,11) [10,22) [21,32) [32,43) [42,54) [53,64)
        if (h <= 10)            c6[0] = fmaxf(c6[0], v);
        if (h >= 10 && h <= 21) c6[1] = fmaxf(c6[1], v);
        if (h >= 21 && h <= 31) c6[2] = fmaxf(c6[2], v);
        if (h >= 32 && h <= 42) c6[3] = fmaxf(c6[3], v);
        if (h >= 42 && h <= 53) c6[4] = fmaxf(c6[4], v);
        if (h >= 53)            c6[5] = fmaxf(c6[5], v);
        // s=8 h-bands: exact [8i, 8i+8)
        d8[h >> 3] = fmaxf(d8[h >> 3], v);
    }

    #pragma unroll
    for (int r = 0; r < 3; ++r) band[wv][r][lane] = b3[r];
    #pragma unroll
    for (int r = 0; r < 6; ++r) band[wv][3 + r][lane] = c6[r];
    #pragma unroll
    for (int r = 0; r < 8; ++r) band[wv][9 + r][lane] = d8[r];

    // s=1: butterfly over all 64 lanes
    #pragma unroll
    for (int off = 32; off; off >>= 1) a0 = fmaxf(a0, __shfl_xor(a0, off));

    __syncthreads();

    const int isK = (c < CK);
    float* dstK = key + ((size_t)b * CK + c) * S_;
    const int cv = c - CK;

    if (lane == 0) {
        if (isK) dstK[0] = a0;
        else     value[((size_t)b * S_ + 0) * CV + cv] = a0;
    }
    // s=8: 64 cells, one per lane; w-windows exact [8j, 8j+8)
    {
        int i = lane >> 3, j = lane & 7;
        const float* row = band[wv][9 + i];
        float m = row[8 * j];
        #pragma unroll
        for (int k = 1; k < 8; ++k) m = fmaxf(m, row[8 * j + k]);
        int sc = 46 + lane;
        if (isK) dstK[sc] = m;
        else     value[((size_t)b * S_ + sc) * CV + cv] = m;
    }
    // s=6: 36 cells on lanes 0..35
    if (lane < 36) {
        int i = lane / 6, j = lane - 6 * i;
        int w0 = (j * 64) / 6, w1 = ((j + 1) * 64 + 5) / 6;
        const float* row = band[wv][3 + i];
        float m = NEG;
        for (int k = w0; k < w1; ++k) m = fmaxf(m, row[k]);
        int sc = 10 + lane;
        if (isK) dstK[sc] = m;
        else     value[((size_t)b * S_ + sc) * CV + cv] = m;
    }
    // s=3: 9 cells on lanes 0..8
    if (lane < 9) {
        int i = lane / 3, j = lane - 3 * i;
        int w0 = (j * 64) / 3, w1 = ((j + 1) * 64 + 2) / 3;
        const float* row = band[wv][i];
        float m = NEG;
        for (int k = w0; k < w1; ++k) m = fmaxf(m, row[k]);
        int sc = 1 + lane;
        if (isK) dstK[sc] = m;
        else     value[((size_t)b * S_ + sc) * CV + cv] = m;
    }
}

// ---------------------------------------------------------------------------
// Kernel: scores = softmax((Q@K)/16), fp32 compute, bf16 Q input.
// ---------------------------------------------------------------------------
__global__ __launch_bounds__(256) void attn_scores_kernel(
    const short* __restrict__ qkb, const float* __restrict__ key,
    float* __restrict__ P)
{
    __shared__ float Aq[64][64];
    __shared__ float Ks[64][112];
    __shared__ float red[4][64];

    const int b  = blockIdx.y;
    const int n0 = blockIdx.x * 64;
    const int tid = threadIdx.x;
    const int nl = tid & 63, g = tid >> 6;
    const int smax = (g == 3) ? 26 : 28;

    float acc[28];
    #pragma unroll
    for (int q = 0; q < 28; ++q) acc[q] = 0.f;

    for (int c0 = 0; c0 < CK; c0 += 64) {
        #pragma unroll
        for (int q = 0; q < 16; ++q) {
            int cc = g + 4 * q;
            Aq[cc][nl] = b2f(qkb[((size_t)b * CK + c0 + cc) * HW + n0 + nl]);
        }
        for (int idx = tid; idx < 64 * S_; idx += 256) {
            int cc = idx / S_, s = idx - cc * S_;
            Ks[cc][s] = key[((size_t)b * CK + c0 + cc) * S_ + s];
        }
        for (int idx = tid; idx < 128; idx += 256)
            Ks[idx >> 1][S_ + (idx & 1)] = 0.f;
        __syncthreads();
        for (int cc = 0; cc < 64; ++cc) {
            float qv = Aq[cc][nl];
            #pragma unroll
            for (int q = 0; q < 28; ++q)
                acc[q] = fmaf(qv, Ks[cc][g * 28 + q], acc[q]);
        }
        __syncthreads();
    }

    float mloc = -1e30f;
    for (int q = 0; q < smax; ++q) { acc[q] *= 0.0625f; mloc = fmaxf(mloc, acc[q]); }
    red[g][nl] = mloc;
    __syncthreads();
    float rmax = fmaxf(fmaxf(red[0][nl], red[1][nl]), fmaxf(red[2][nl], red[3][nl]));
    __syncthreads();
    float sloc = 0.f;
    for (int q = 0; q < smax; ++q) { float e = __expf(acc[q] - rmax); acc[q] = e; sloc += e; }
    red[g][nl] = sloc;
    __syncthreads();
    float rsum = red[0][nl] + red[1][nl] + red[2][nl] + red[3][nl];
    float inv = 1.f / rsum;
    float* Prow = P + ((size_t)b * HW + n0 + nl) * S_ + g * 28;
    for (int q = 0; q < smax; ++q) Prow[q] = acc[q] * inv;
}

// ---------------------------------------------------------------------------
// Kernel: Yt[b][n][cv] (bf16) = sum_s P[b][n][s] * value[b][s][cv]
// ---------------------------------------------------------------------------
__global__ __launch_bounds__(256) void attn_pv_kernel(
    const float* __restrict__ P, const float* __restrict__ value,
    short* __restrict__ Yt)
{
    __shared__ float Vs[S_][64];
    __shared__ float Pt[S_][64];

    const int b = blockIdx.z, cv0 = blockIdx.y * 64, n0 = blockIdx.x * 64;
    const int tid = threadIdx.x;
    const int nn = tid & 63, sr = tid >> 6;
    const int tx = tid & 15, ty = tid >> 4;   // tx -> cv, ty -> n

    for (int s = sr; s < S_; s += 4)
        Vs[s][nn] = value[((size_t)b * S_ + s) * CV + cv0 + nn];
    for (int s = sr; s < S_; s += 4)
        Pt[s][nn] = P[((size_t)b * HW + n0 + nn) * S_ + s];
    __syncthreads();

    float acc[4][4] = {};  // [i: n][j: cv]
    for (int s = 0; s < S_; ++s) {
        float a[4], vv[4];
        #pragma unroll
        for (int i = 0; i < 4; ++i) a[i] = Pt[s][ty * 4 + i];
        #pragma unroll
        for (int j = 0; j < 4; ++j) vv[j] = Vs[s][tx * 4 + j];
        #pragma unroll
        for (int i = 0; i < 4; ++i)
            #pragma unroll
            for (int j = 0; j < 4; ++j)
                acc[i][j] = fmaf(a[i], vv[j], acc[i][j]);
    }
    #pragma unroll
    for (int i = 0; i < 4; ++i) {
        short* dst = Yt + ((size_t)b * HW + n0 + ty * 4 + i) * CV + cv0 + tx * 4;
        bf16x4 v;
        #pragma unroll
        for (int j = 0; j < 4; ++j) v[j] = f2b(acc[i][j]);
        *(bf16x4*)dst = v;
    }
}

// ---------------------------------------------------------------------------
// Launch
// ---------------------------------------------------------------------------
extern "C" void kernel_launch(void* const* d_in, const int* in_sizes, int n_in,
                              void* d_out, int out_size, void* d_ws, size_t ws_size,
                              hipStream_t stream)
{
    const float* x        = (const float*)d_in[0];
    const float* qk_w     = (const float*)d_in[1];
    const float* qk_gamma = (const float*)d_in[2];
    const float* qk_beta  = (const float*)d_in[3];
    const float* qk_mean  = (const float*)d_in[4];
    const float* qk_var   = (const float*)d_in[5];
    const float* v_w      = (const float*)d_in[6];
    const float* v_gamma  = (const float*)d_in[7];
    const float* v_beta   = (const float*)d_in[8];
    const float* v_mean   = (const float*)d_in[9];
    const float* v_var    = (const float*)d_in[10];
    const float* out_w    = (const float*)d_in[11];
    const float* out_gamma= (const float*)d_in[12];
    const float* out_beta = (const float*)d_in[13];
    const float* out_mean = (const float*)d_in[14];
    const float* out_var  = (const float*)d_in[15];

    char* wsb = (char*)d_ws;
    short* xt    = (short*)(wsb);                 // [8][4096][512] bf16  33.5 MB
    short* qkb   = (short*)(wsb + 33554432);      // [8][256][4096] bf16  16.8 MB
    short* valb  = (short*)(wsb + 50331648);      // [8][512][4096] bf16  33.5 MB
    short* Yt    = valb;                          // aliases valb (dead after pool)
    float* key   = (float*)(wsb + 83886080);      // [8][256][110]
    float* value = (float*)(wsb + 84787200);      // [8][110][512]
    float* P     = (float*)(wsb + 86589440);      // [8][4096][110]
    short* wqkv  = (short*)(wsb + 101007360);     // [768][512]
    short* wout  = wqkv + 393216;                 // [512][512]

    transpose_x_kernel<<<dim3(HW / 64, CIN / 64, B_), 256, 0, stream>>>(x, xt);
    convert_w_kernel<<<dim3(640), 256, 0, stream>>>(qk_w, v_w, out_w, wqkv);

    gemm_mfma_kernel<0><<<dim3(HW / 128, 6, B_), 256, 0, stream>>>(
        wqkv, xt, qk_gamma, qk_beta, qk_mean, qk_var,
        v_gamma, v_beta, v_mean, v_var,
        nullptr, qkb, valb, nullptr);

    psp_pool_kernel<<<dim3((CK + CV) / 4, B_), 256, 0, stream>>>(qkb, valb, key, value);

    attn_scores_kernel<<<dim3(HW / 64, B_), 256, 0, stream>>>(qkb, key, P);

    attn_pv_kernel<<<dim3(HW / 64, CV / 64, B_), 256, 0, stream>>>(P, value, Yt);

    gemm_mfma_kernel<1><<<dim3(HW / 128, 4, B_), 256, 0, stream>>>(
        wout, Yt, out_gamma, out_beta, out_mean, out_var,
        nullptr, nullptr, nullptr, nullptr,
        x, nullptr, nullptr, (float*)d_out);
}

// Round 7
// 274.396 us; speedup vs baseline: 4.0468x; 1.4219x over previous
//
#include <hip/hip_runtime.h>
#include <math.h>

#define B_    8
#define CIN   512
#define CK    256
#define CV    512
#define HW    4096
#define S_    110
#define SP    128          // padded S for MFMA
#define EPS   1e-5f

typedef __attribute__((ext_vector_type(8))) short bf16x8;
typedef __attribute__((ext_vector_type(4))) short bf16x4;
typedef __attribute__((ext_vector_type(4))) float f32x4;

__device__ __forceinline__ float b2f(short s) {
    unsigned int u = ((unsigned int)(unsigned short)s) << 16;
    union { unsigned int u; float f; } c; c.u = u; return c.f;
}
__device__ __forceinline__ short f2b(float f) {
    union { float f; unsigned int u; } c; c.f = f;
    unsigned int r = (c.u + 0x7FFFu + ((c.u >> 16) & 1u)) >> 16;   // RNE
    return (short)r;
}

// ---------------------------------------------------------------------------
// x [b][c][n] fp32 -> xt [b][n][c] bf16
// ---------------------------------------------------------------------------
__global__ __launch_bounds__(256) void transpose_x_kernel(
    const float* __restrict__ x, short* __restrict__ xt)
{
    __shared__ short t[64][65];
    const int b = blockIdx.z, c0 = blockIdx.y * 64, n0 = blockIdx.x * 64;
    const int tid = threadIdx.x;
    const float* src = x + ((size_t)b * CIN + c0) * HW + n0;
    const int j = tid & 63, i0 = tid >> 6;
    #pragma unroll
    for (int q = 0; q < 16; ++q) {
        int i = i0 * 16 + q;
        t[i][j] = f2b(src[(size_t)i * HW + j]);
    }
    __syncthreads();
    short* dst = xt + ((size_t)b * HW + n0) * CIN + c0;
    const int hh = tid & 31, jb = tid >> 5;
    #pragma unroll
    for (int q = 0; q < 8; ++q) {
        int jj = jb * 8 + q;
        short2 v; v.x = t[2 * hh][jj]; v.y = t[2 * hh + 1][jj];
        *(short2*)(dst + (size_t)jj * CIN + 2 * hh) = v;
    }
}

// ---------------------------------------------------------------------------
// qkb [b][c][n] bf16 -> qkt [b][n][c] bf16
// ---------------------------------------------------------------------------
__global__ __launch_bounds__(256) void transpose_qk_kernel(
    const short* __restrict__ qkb, short* __restrict__ qkt)
{
    __shared__ short t[64][65];
    const int b = blockIdx.z, c0 = blockIdx.y * 64, n0 = blockIdx.x * 64;
    const int tid = threadIdx.x;
    const short* src = qkb + ((size_t)b * CK + c0) * HW + n0;
    const int j = tid & 63, i0 = tid >> 6;
    #pragma unroll
    for (int q = 0; q < 16; ++q) {
        int i = i0 * 16 + q;
        t[i][j] = src[(size_t)i * HW + j];
    }
    __syncthreads();
    short* dst = qkt + ((size_t)b * HW + n0) * CK + c0;
    const int hh = tid & 31, jb = tid >> 5;
    #pragma unroll
    for (int q = 0; q < 8; ++q) {
        int jj = jb * 8 + q;
        short2 v; v.x = t[2 * hh][jj]; v.y = t[2 * hh + 1][jj];
        *(short2*)(dst + (size_t)jj * CK + 2 * hh) = v;
    }
}

// ---------------------------------------------------------------------------
// weights fp32 -> bf16
// ---------------------------------------------------------------------------
__global__ __launch_bounds__(256) void convert_w_kernel(
    const float* __restrict__ qk_w, const float* __restrict__ v_w,
    const float* __restrict__ out_w, short* __restrict__ wb)
{
    const int id4 = (blockIdx.x * 256 + threadIdx.x) * 4;
    #pragma unroll
    for (int r = 0; r < 4; ++r) {
        int id = id4 + r;
        float f = (id < 131072) ? qk_w[id]
                : (id < 393216) ? v_w[id - 131072]
                                : out_w[id - 393216];
        wb[id] = f2b(f);
    }
}

// ---------------------------------------------------------------------------
// MFMA GEMM (convs): C[co][n] = sum_k W[co][k] * Bt[n][k]
// ---------------------------------------------------------------------------
template<int MODE>
__global__ __launch_bounds__(256) void gemm_mfma_kernel(
    const short* __restrict__ W, const short* __restrict__ Bt,
    const float* __restrict__ g0, const float* __restrict__ be0,
    const float* __restrict__ mu0, const float* __restrict__ va0,
    const float* __restrict__ g1, const float* __restrict__ be1,
    const float* __restrict__ mu1, const float* __restrict__ va1,
    const float* __restrict__ xres,
    short* __restrict__ o0, short* __restrict__ o1,
    float* __restrict__ of)
{
    __shared__ short As[128 * 64];
    __shared__ short Bs[128 * 64];
    const int b   = blockIdx.z;
    const int mm0 = blockIdx.y * 128, nn0 = blockIdx.x * 128;
    const int tid = threadIdx.x;
    const int lane = tid & 63, wv = tid >> 6;
    const int wm = (wv >> 1) * 64, wn = (wv & 1) * 64;
    const int l15 = lane & 15, l4 = lane >> 4;

    const int srow = tid >> 1, shalf = tid & 1;
    const short* wsrc = W + (size_t)(mm0 + srow) * 512 + shalf * 32;
    const short* xsrc = Bt + ((size_t)b * HW + nn0 + srow) * 512 + shalf * 32;
    int woff[4];
    #pragma unroll
    for (int q = 0; q < 4; ++q) {
        int unit = shalf * 4 + q;
        woff[q] = srow * 64 + (unit ^ (srow & 7)) * 8;
    }

    f32x4 acc[4][4] = {};

    for (int kt = 0; kt < 512; kt += 64) {
        #pragma unroll
        for (int q = 0; q < 4; ++q)
            *(bf16x8*)&As[woff[q]] = *(const bf16x8*)(wsrc + kt + q * 8);
        #pragma unroll
        for (int q = 0; q < 4; ++q)
            *(bf16x8*)&Bs[woff[q]] = *(const bf16x8*)(xsrc + kt + q * 8);
        __syncthreads();
        #pragma unroll
        for (int kk = 0; kk < 2; ++kk) {
            bf16x8 af[4], bfr[4];
            #pragma unroll
            for (int m = 0; m < 4; ++m) {
                int row = wm + m * 16 + l15;
                int su = (kk * 4 + l4) ^ (row & 7);
                af[m] = *(const bf16x8*)&As[row * 64 + su * 8];
            }
            #pragma unroll
            for (int n = 0; n < 4; ++n) {
                int row = wn + n * 16 + l15;
                int su = (kk * 4 + l4) ^ (row & 7);
                bfr[n] = *(const bf16x8*)&Bs[row * 64 + su * 8];
            }
            #pragma unroll
            for (int m = 0; m < 4; ++m)
                #pragma unroll
                for (int n = 0; n < 4; ++n)
                    acc[m][n] = __builtin_amdgcn_mfma_f32_16x16x32_bf16(
                        af[m], bfr[n], acc[m][n], 0, 0, 0);
        }
        __syncthreads();
    }

    #pragma unroll
    for (int m = 0; m < 4; ++m) {
        #pragma unroll
        for (int i = 0; i < 4; ++i) {
            const int co = mm0 + wm + m * 16 + l4 * 4 + i;
            if (MODE == 0) {
                float sc, sh; short* dst;
                if (co < CK) {
                    sc = g0[co] * rsqrtf(va0[co] + EPS);
                    sh = be0[co] - mu0[co] * sc;
                    dst = o0 + ((size_t)b * CK + co) * HW;
                } else {
                    int cv = co - CK;
                    sc = g1[cv] * rsqrtf(va1[cv] + EPS);
                    sh = be1[cv] - mu1[cv] * sc;
                    dst = o1 + ((size_t)b * CV + cv) * HW;
                }
                #pragma unroll
                for (int n = 0; n < 4; ++n) {
                    float v = fmaxf(acc[m][n][i] * sc + sh, 0.f);
                    dst[nn0 + wn + n * 16 + l15] = f2b(v);
                }
            } else {
                float sc = g0[co] * rsqrtf(va0[co] + EPS);
                float sh = be0[co] - mu0[co] * sc;
                const float* xr = xres + ((size_t)b * CIN + co) * HW;
                float* orow = of + ((size_t)b * CIN + co) * HW;
                #pragma unroll
                for (int n = 0; n < 4; ++n) {
                    int nidx = nn0 + wn + n * 16 + l15;
                    orow[nidx] = acc[m][n][i] * sc + sh + xr[nidx];
                }
            }
        }
    }
}

// ---------------------------------------------------------------------------
// PSP pool — separable, wave-per-plane. Writes TRANSPOSED bf16 pools:
//   keyT[b][s][c] (c-contig rows for scores B-operand)
//   valueT[b][cv][s] (s-contig rows for PV B-operand, s padded to 128)
// ---------------------------------------------------------------------------
__global__ __launch_bounds__(256) void psp_pool_kernel(
    const short* __restrict__ qkb, const short* __restrict__ valb,
    short* __restrict__ keyT, short* __restrict__ valueT)
{
    __shared__ float band[4][17][64];
    const int tid = threadIdx.x;
    const int lane = tid & 63, wv = tid >> 6;
    const int c = blockIdx.x * 4 + wv;
    const int b = blockIdx.y;

    const short* src = (c < CK) ? qkb + ((size_t)b * CK + c) * HW
                                : valb + ((size_t)b * CV + (c - CK)) * HW;

    const float NEG = -1e30f;
    float a0 = NEG;
    float b3[3] = {NEG, NEG, NEG};
    float c6[6] = {NEG, NEG, NEG, NEG, NEG, NEG};
    float d8[8] = {NEG, NEG, NEG, NEG, NEG, NEG, NEG, NEG};

    #pragma unroll
    for (int h = 0; h < 64; ++h) {
        float v = b2f(src[h * 64 + lane]);
        a0 = fmaxf(a0, v);
        if (h <= 21)            b3[0] = fmaxf(b3[0], v);
        if (h >= 21 && h <= 42) b3[1] = fmaxf(b3[1], v);
        if (h >= 42)            b3[2] = fmaxf(b3[2], v);
        if (h <= 10)            c6[0] = fmaxf(c6[0], v);
        if (h >= 10 && h <= 21) c6[1] = fmaxf(c6[1], v);
        if (h >= 21 && h <= 31) c6[2] = fmaxf(c6[2], v);
        if (h >= 32 && h <= 42) c6[3] = fmaxf(c6[3], v);
        if (h >= 42 && h <= 53) c6[4] = fmaxf(c6[4], v);
        if (h >= 53)            c6[5] = fmaxf(c6[5], v);
        d8[h >> 3] = fmaxf(d8[h >> 3], v);
    }

    #pragma unroll
    for (int r = 0; r < 3; ++r) band[wv][r][lane] = b3[r];
    #pragma unroll
    for (int r = 0; r < 6; ++r) band[wv][3 + r][lane] = c6[r];
    #pragma unroll
    for (int r = 0; r < 8; ++r) band[wv][9 + r][lane] = d8[r];

    #pragma unroll
    for (int off = 32; off; off >>= 1) a0 = fmaxf(a0, __shfl_xor(a0, off));

    __syncthreads();

    const int isK = (c < CK);
    const int cv = c - CK;

    if (lane == 0) {
        if (isK) keyT[((size_t)b * SP + 0) * CK + c] = f2b(a0);
        else     valueT[((size_t)b * CV + cv) * SP + 0] = f2b(a0);
    }
    {   // s=8: 64 cells
        int i = lane >> 3, j = lane & 7;
        const float* row = band[wv][9 + i];
        float m = row[8 * j];
        #pragma unroll
        for (int k = 1; k < 8; ++k) m = fmaxf(m, row[8 * j + k]);
        int sc = 46 + lane;
        if (isK) keyT[((size_t)b * SP + sc) * CK + c] = f2b(m);
        else     valueT[((size_t)b * CV + cv) * SP + sc] = f2b(m);
    }
    if (lane < 36) {   // s=6
        int i = lane / 6, j = lane - 6 * i;
        int w0 = (j * 64) / 6, w1 = ((j + 1) * 64 + 5) / 6;
        const float* row = band[wv][3 + i];
        float m = NEG;
        for (int k = w0; k < w1; ++k) m = fmaxf(m, row[k]);
        int sc = 10 + lane;
        if (isK) keyT[((size_t)b * SP + sc) * CK + c] = f2b(m);
        else     valueT[((size_t)b * CV + cv) * SP + sc] = f2b(m);
    }
    if (lane < 9) {    // s=3
        int i = lane / 3, j = lane - 3 * i;
        int w0 = (j * 64) / 3, w1 = ((j + 1) * 64 + 2) / 3;
        const float* row = band[wv][i];
        float m = NEG;
        for (int k = w0; k < w1; ++k) m = fmaxf(m, row[k]);
        int sc = 1 + lane;
        if (isK) keyT[((size_t)b * SP + sc) * CK + c] = f2b(m);
        else     valueT[((size_t)b * CV + cv) * SP + sc] = f2b(m);
    }
}

// ---------------------------------------------------------------------------
// Scores MFMA + fused softmax: P[b][n][s] = softmax_s(Q·K/16), bf16 out.
//   A = qkt[b][n][c], B = keyT[b][s][c]; M-tile 128 n x full 128 s; K=256.
//   s in [110,128) masked to -1e30 -> P=0 exactly.
// ---------------------------------------------------------------------------
__global__ __launch_bounds__(256) void attn_scores_mfma_kernel(
    const short* __restrict__ qkt, const short* __restrict__ keyT,
    short* __restrict__ P)
{
    __shared__ short As[128 * 64];
    __shared__ short Bs[128 * 64];
    __shared__ float red[2][2][128];
    const int b  = blockIdx.y;
    const int m0 = blockIdx.x * 128;
    const int tid = threadIdx.x;
    const int lane = tid & 63, wv = tid >> 6;
    const int wm = (wv >> 1) * 64, wn = (wv & 1) * 64;
    const int l15 = lane & 15, l4 = lane >> 4;

    const int srow = tid >> 1, shalf = tid & 1;
    const short* asrc = qkt + ((size_t)b * HW + m0 + srow) * CK + shalf * 32;
    const short* bsrc = keyT + ((size_t)b * SP + srow) * CK + shalf * 32;
    int woff[4];
    #pragma unroll
    for (int q = 0; q < 4; ++q) {
        int unit = shalf * 4 + q;
        woff[q] = srow * 64 + (unit ^ (srow & 7)) * 8;
    }

    f32x4 acc[4][4] = {};

    for (int kt = 0; kt < CK; kt += 64) {
        #pragma unroll
        for (int q = 0; q < 4; ++q)
            *(bf16x8*)&As[woff[q]] = *(const bf16x8*)(asrc + kt + q * 8);
        #pragma unroll
        for (int q = 0; q < 4; ++q)
            *(bf16x8*)&Bs[woff[q]] = *(const bf16x8*)(bsrc + kt + q * 8);
        __syncthreads();
        #pragma unroll
        for (int kk = 0; kk < 2; ++kk) {
            bf16x8 af[4], bfr[4];
            #pragma unroll
            for (int m = 0; m < 4; ++m) {
                int row = wm + m * 16 + l15;
                int su = (kk * 4 + l4) ^ (row & 7);
                af[m] = *(const bf16x8*)&As[row * 64 + su * 8];
            }
            #pragma unroll
            for (int n = 0; n < 4; ++n) {
                int row = wn + n * 16 + l15;
                int su = (kk * 4 + l4) ^ (row & 7);
                bfr[n] = *(const bf16x8*)&Bs[row * 64 + su * 8];
            }
            #pragma unroll
            for (int m = 0; m < 4; ++m)
                #pragma unroll
                for (int n = 0; n < 4; ++n)
                    acc[m][n] = __builtin_amdgcn_mfma_f32_16x16x32_bf16(
                        af[m], bfr[n], acc[m][n], 0, 0, 0);
        }
        __syncthreads();
    }

    // ---- fused softmax over s ----
    // lane holds rows (wm + m*16 + l4*4 + i), cols s = wn + n*16 + l15
    float pv[4][4][4];   // [m][n][i]
    float rmax[4][4], rsum[4][4];
    #pragma unroll
    for (int m = 0; m < 4; ++m)
        #pragma unroll
        for (int i = 0; i < 4; ++i) {
            float mx = -1e30f;
            #pragma unroll
            for (int n = 0; n < 4; ++n) {
                int s = wn + n * 16 + l15;
                float v = acc[m][n][i] * 0.0625f;
                if (s >= S_) v = -1e30f;
                pv[m][n][i] = v;
                mx = fmaxf(mx, v);
            }
            rmax[m][i] = mx;
        }
    #pragma unroll
    for (int off = 1; off < 16; off <<= 1)
        #pragma unroll
        for (int m = 0; m < 4; ++m)
            #pragma unroll
            for (int i = 0; i < 4; ++i)
                rmax[m][i] = fmaxf(rmax[m][i], __shfl_xor(rmax[m][i], off));
    if (l15 == 0) {
        #pragma unroll
        for (int m = 0; m < 4; ++m)
            #pragma unroll
            for (int i = 0; i < 4; ++i)
                red[0][wv & 1][wm + m * 16 + l4 * 4 + i] = rmax[m][i];
    }
    __syncthreads();
    #pragma unroll
    for (int m = 0; m < 4; ++m)
        #pragma unroll
        for (int i = 0; i < 4; ++i) {
            float gmax = fmaxf(rmax[m][i], red[0][(wv & 1) ^ 1][wm + m * 16 + l4 * 4 + i]);
            float sm = 0.f;
            #pragma unroll
            for (int n = 0; n < 4; ++n) {
                float e = __expf(pv[m][n][i] - gmax);
                pv[m][n][i] = e;
                sm += e;
            }
            rsum[m][i] = sm;
        }
    #pragma unroll
    for (int off = 1; off < 16; off <<= 1)
        #pragma unroll
        for (int m = 0; m < 4; ++m)
            #pragma unroll
            for (int i = 0; i < 4; ++i)
                rsum[m][i] += __shfl_xor(rsum[m][i], off);
    if (l15 == 0) {
        #pragma unroll
        for (int m = 0; m < 4; ++m)
            #pragma unroll
            for (int i = 0; i < 4; ++i)
                red[1][wv & 1][wm + m * 16 + l4 * 4 + i] = rsum[m][i];
    }
    __syncthreads();
    #pragma unroll
    for (int m = 0; m < 4; ++m)
        #pragma unroll
        for (int i = 0; i < 4; ++i) {
            int row = wm + m * 16 + l4 * 4 + i;
            float inv = 1.f / (rsum[m][i] + red[1][(wv & 1) ^ 1][row]);
            short* dst = P + ((size_t)b * HW + m0 + row) * SP + wn + l15;
            #pragma unroll
            for (int n = 0; n < 4; ++n)
                dst[n * 16] = f2b(pv[m][n][i] * inv);
        }
}

// ---------------------------------------------------------------------------
// PV MFMA: Yt[b][n][cv] = sum_s P[n][s] * valueT[cv][s], bf16 out. K=128.
// ---------------------------------------------------------------------------
__global__ __launch_bounds__(256) void attn_pv_mfma_kernel(
    const short* __restrict__ P, const short* __restrict__ valueT,
    short* __restrict__ Yt)
{
    __shared__ short As[128 * 64];
    __shared__ short Bs[128 * 64];
    const int b   = blockIdx.z;
    const int m0  = blockIdx.y * 128;    // n-rows
    const int cv0 = blockIdx.x * 128;    // cv cols
    const int tid = threadIdx.x;
    const int lane = tid & 63, wv = tid >> 6;
    const int wm = (wv >> 1) * 64, wn = (wv & 1) * 64;
    const int l15 = lane & 15, l4 = lane >> 4;

    const int srow = tid >> 1, shalf = tid & 1;
    const short* asrc = P + ((size_t)b * HW + m0 + srow) * SP + shalf * 32;
    const short* bsrc = valueT + ((size_t)b * CV + cv0 + srow) * SP + shalf * 32;
    int woff[4];
    #pragma unroll
    for (int q = 0; q < 4; ++q) {
        int unit = shalf * 4 + q;
        woff[q] = srow * 64 + (unit ^ (srow & 7)) * 8;
    }

    f32x4 acc[4][4] = {};

    for (int kt = 0; kt < SP; kt += 64) {
        #pragma unroll
        for (int q = 0; q < 4; ++q)
            *(bf16x8*)&As[woff[q]] = *(const bf16x8*)(asrc + kt + q * 8);
        #pragma unroll
        for (int q = 0; q < 4; ++q)
            *(bf16x8*)&Bs[woff[q]] = *(const bf16x8*)(bsrc + kt + q * 8);
        __syncthreads();
        #pragma unroll
        for (int kk = 0; kk < 2; ++kk) {
            bf16x8 af[4], bfr[4];
            #pragma unroll
            for (int m = 0; m < 4; ++m) {
                int row = wm + m * 16 + l15;
                int su = (kk * 4 + l4) ^ (row & 7);
                af[m] = *(const bf16x8*)&As[row * 64 + su * 8];
            }
            #pragma unroll
            for (int n = 0; n < 4; ++n) {
                int row = wn + n * 16 + l15;
                int su = (kk * 4 + l4) ^ (row & 7);
                bfr[n] = *(const bf16x8*)&Bs[row * 64 + su * 8];
            }
            #pragma unroll
            for (int m = 0; m < 4; ++m)
                #pragma unroll
                for (int n = 0; n < 4; ++n)
                    acc[m][n] = __builtin_amdgcn_mfma_f32_16x16x32_bf16(
                        af[m], bfr[n], acc[m][n], 0, 0, 0);
        }
        __syncthreads();
    }

    #pragma unroll
    for (int m = 0; m < 4; ++m)
        #pragma unroll
        for (int i = 0; i < 4; ++i) {
            int row = wm + m * 16 + l4 * 4 + i;
            short* dst = Yt + ((size_t)b * HW + m0 + row) * CV + cv0 + wn + l15;
            #pragma unroll
            for (int n = 0; n < 4; ++n)
                dst[n * 16] = f2b(acc[m][n][i]);
        }
}

// ---------------------------------------------------------------------------
// Launch
// ---------------------------------------------------------------------------
extern "C" void kernel_launch(void* const* d_in, const int* in_sizes, int n_in,
                              void* d_out, int out_size, void* d_ws, size_t ws_size,
                              hipStream_t stream)
{
    const float* x        = (const float*)d_in[0];
    const float* qk_w     = (const float*)d_in[1];
    const float* qk_gamma = (const float*)d_in[2];
    const float* qk_beta  = (const float*)d_in[3];
    const float* qk_mean  = (const float*)d_in[4];
    const float* qk_var   = (const float*)d_in[5];
    const float* v_w      = (const float*)d_in[6];
    const float* v_gamma  = (const float*)d_in[7];
    const float* v_beta   = (const float*)d_in[8];
    const float* v_mean   = (const float*)d_in[9];
    const float* v_var    = (const float*)d_in[10];
    const float* out_w    = (const float*)d_in[11];
    const float* out_gamma= (const float*)d_in[12];
    const float* out_beta = (const float*)d_in[13];
    const float* out_mean = (const float*)d_in[14];
    const float* out_var  = (const float*)d_in[15];

    char* wsb = (char*)d_ws;
    short* xt     = (short*)(wsb);                 // [8][4096][512] bf16 33.5MB
    short* qkt    = xt;                            // [8][4096][256] bf16 (aliases xt; xt dead after gemm<0>)
    short* qkb    = (short*)(wsb + 33554432);      // [8][256][4096] bf16 16.8MB
    short* valb   = (short*)(wsb + 50331648);      // [8][512][4096] bf16 33.5MB
    short* Yt     = valb;                          // aliases valb (dead after pool)
    short* keyT   = (short*)(wsb + 83886080);      // [8][128][256] bf16 0.5MB
    short* valueT = (short*)(wsb + 84410368);      // [8][512][128] bf16 1MB
    short* P      = (short*)(wsb + 85458944);      // [8][4096][128] bf16 8.4MB
    short* wqkv   = (short*)(wsb + 93847552);      // [768][512]
    short* wout   = wqkv + 393216;                 // [512][512]

    transpose_x_kernel<<<dim3(HW / 64, CIN / 64, B_), 256, 0, stream>>>(x, xt);
    convert_w_kernel<<<dim3(640), 256, 0, stream>>>(qk_w, v_w, out_w, wqkv);

    gemm_mfma_kernel<0><<<dim3(HW / 128, 6, B_), 256, 0, stream>>>(
        wqkv, xt, qk_gamma, qk_beta, qk_mean, qk_var,
        v_gamma, v_beta, v_mean, v_var,
        nullptr, qkb, valb, nullptr);

    transpose_qk_kernel<<<dim3(HW / 64, CK / 64, B_), 256, 0, stream>>>(qkb, qkt);

    psp_pool_kernel<<<dim3((CK + CV) / 4, B_), 256, 0, stream>>>(qkb, valb, keyT, valueT);

    attn_scores_mfma_kernel<<<dim3(HW / 128, B_), 256, 0, stream>>>(qkt, keyT, P);

    attn_pv_mfma_kernel<<<dim3(CV / 128, HW / 128, B_), 256, 0, stream>>>(P, valueT, Yt);

    gemm_mfma_kernel<1><<<dim3(HW / 128, 4, B_), 256, 0, stream>>>(
        wout, Yt, out_gamma, out_beta, out_mean, out_var,
        nullptr, nullptr, nullptr, nullptr,
        x, nullptr, nullptr, (float*)d_out);
}

// Round 8
// 272.700 us; speedup vs baseline: 4.0720x; 1.0062x over previous
//
#include <hip/hip_runtime.h>
#include <math.h>

#define B_    8
#define CIN   512
#define CK    256
#define CV    512
#define HW    4096
#define S_    110
#define SP    128          // padded S for MFMA
#define EPS   1e-5f

typedef __attribute__((ext_vector_type(8))) short bf16x8;
typedef __attribute__((ext_vector_type(4))) short bf16x4;
typedef __attribute__((ext_vector_type(4))) float f32x4;

__device__ __forceinline__ float b2f(short s) {
    unsigned int u = ((unsigned int)(unsigned short)s) << 16;
    union { unsigned int u; float f; } c; c.u = u; return c.f;
}
__device__ __forceinline__ short f2b(float f) {
    union { float f; unsigned int u; } c; c.f = f;
    unsigned int r = (c.u + 0x7FFFu + ((c.u >> 16) & 1u)) >> 16;   // RNE
    return (short)r;
}

// async global->LDS, 16B per lane, wave-linear LDS dest
__device__ __forceinline__ void gload_lds16(const short* g, short* l) {
    __builtin_amdgcn_global_load_lds(
        (const __attribute__((address_space(1))) void*)g,
        (__attribute__((address_space(3))) void*)l,
        16, 0, 0);
}

// Stage a 128-row x 64-short tile (XOR-swizzled) via global_load_lds.
// LDS unit u (row=u>>3, slot=u&7) receives global k-unit (slot ^ (row&7)),
// so LDS[row][s] = global[row][s ^ (row&7)] — identical layout to the old
// reg-staged writes; swizzled ds_read side unchanged.
template<int STRIDE>
__device__ __forceinline__ void stage_tile(
    const short* __restrict__ base, short* lds, int tid, int kt)
{
    const int wv = tid >> 6, lane = tid & 63;
    #pragma unroll
    for (int q = 0; q < 4; ++q) {
        const int u = q * 256 + wv * 64 + lane;      // 16B-unit index [0,1024)
        const int row = u >> 3;
        const int kunit = (u & 7) ^ (row & 7);
        gload_lds16(base + (size_t)row * STRIDE + kt + kunit * 8,
                    lds + (q * 256 + wv * 64) * 8);  // wave-uniform base
    }
}

// ---------------------------------------------------------------------------
// x [b][c][n] fp32 -> xt [b][n][c] bf16
// ---------------------------------------------------------------------------
__global__ __launch_bounds__(256) void transpose_x_kernel(
    const float* __restrict__ x, short* __restrict__ xt)
{
    __shared__ short t[64][65];
    const int b = blockIdx.z, c0 = blockIdx.y * 64, n0 = blockIdx.x * 64;
    const int tid = threadIdx.x;
    const float* src = x + ((size_t)b * CIN + c0) * HW + n0;
    const int j = tid & 63, i0 = tid >> 6;
    #pragma unroll
    for (int q = 0; q < 16; ++q) {
        int i = i0 * 16 + q;
        t[i][j] = f2b(src[(size_t)i * HW + j]);
    }
    __syncthreads();
    short* dst = xt + ((size_t)b * HW + n0) * CIN + c0;
    const int hh = tid & 31, jb = tid >> 5;
    #pragma unroll
    for (int q = 0; q < 8; ++q) {
        int jj = jb * 8 + q;
        short2 v; v.x = t[2 * hh][jj]; v.y = t[2 * hh + 1][jj];
        *(short2*)(dst + (size_t)jj * CIN + 2 * hh) = v;
    }
}

// ---------------------------------------------------------------------------
// qkb [b][c][n] bf16 -> qkt [b][n][c] bf16
// ---------------------------------------------------------------------------
__global__ __launch_bounds__(256) void transpose_qk_kernel(
    const short* __restrict__ qkb, short* __restrict__ qkt)
{
    __shared__ short t[64][65];
    const int b = blockIdx.z, c0 = blockIdx.y * 64, n0 = blockIdx.x * 64;
    const int tid = threadIdx.x;
    const short* src = qkb + ((size_t)b * CK + c0) * HW + n0;
    const int j = tid & 63, i0 = tid >> 6;
    #pragma unroll
    for (int q = 0; q < 16; ++q) {
        int i = i0 * 16 + q;
        t[i][j] = src[(size_t)i * HW + j];
    }
    __syncthreads();
    short* dst = qkt + ((size_t)b * HW + n0) * CK + c0;
    const int hh = tid & 31, jb = tid >> 5;
    #pragma unroll
    for (int q = 0; q < 8; ++q) {
        int jj = jb * 8 + q;
        short2 v; v.x = t[2 * hh][jj]; v.y = t[2 * hh + 1][jj];
        *(short2*)(dst + (size_t)jj * CK + 2 * hh) = v;
    }
}

// ---------------------------------------------------------------------------
// weights fp32 -> bf16
// ---------------------------------------------------------------------------
__global__ __launch_bounds__(256) void convert_w_kernel(
    const float* __restrict__ qk_w, const float* __restrict__ v_w,
    const float* __restrict__ out_w, short* __restrict__ wb)
{
    const int id4 = (blockIdx.x * 256 + threadIdx.x) * 4;
    #pragma unroll
    for (int r = 0; r < 4; ++r) {
        int id = id4 + r;
        float f = (id < 131072) ? qk_w[id]
                : (id < 393216) ? v_w[id - 131072]
                                : out_w[id - 393216];
        wb[id] = f2b(f);
    }
}

// ---------------------------------------------------------------------------
// MFMA GEMM (convs): C[co][n] = sum_k W[co][k] * Bt[n][k]
// ---------------------------------------------------------------------------
template<int MODE>
__global__ __launch_bounds__(256) void gemm_mfma_kernel(
    const short* __restrict__ W, const short* __restrict__ Bt,
    const float* __restrict__ g0, const float* __restrict__ be0,
    const float* __restrict__ mu0, const float* __restrict__ va0,
    const float* __restrict__ g1, const float* __restrict__ be1,
    const float* __restrict__ mu1, const float* __restrict__ va1,
    const float* __restrict__ xres,
    short* __restrict__ o0, short* __restrict__ o1,
    float* __restrict__ of)
{
    __shared__ short As[128 * 64];
    __shared__ short Bs[128 * 64];
    const int b   = blockIdx.z;
    const int mm0 = blockIdx.y * 128, nn0 = blockIdx.x * 128;
    const int tid = threadIdx.x;
    const int lane = tid & 63, wv = tid >> 6;
    const int wm = (wv >> 1) * 64, wn = (wv & 1) * 64;
    const int l15 = lane & 15, l4 = lane >> 4;

    const short* wbase = W + (size_t)mm0 * 512;
    const short* xbase = Bt + ((size_t)b * HW + nn0) * 512;

    f32x4 acc[4][4] = {};

    for (int kt = 0; kt < 512; kt += 64) {
        stage_tile<512>(wbase, As, tid, kt);
        stage_tile<512>(xbase, Bs, tid, kt);
        __syncthreads();
        #pragma unroll
        for (int kk = 0; kk < 2; ++kk) {
            bf16x8 af[4], bfr[4];
            #pragma unroll
            for (int m = 0; m < 4; ++m) {
                int row = wm + m * 16 + l15;
                int su = (kk * 4 + l4) ^ (row & 7);
                af[m] = *(const bf16x8*)&As[row * 64 + su * 8];
            }
            #pragma unroll
            for (int n = 0; n < 4; ++n) {
                int row = wn + n * 16 + l15;
                int su = (kk * 4 + l4) ^ (row & 7);
                bfr[n] = *(const bf16x8*)&Bs[row * 64 + su * 8];
            }
            #pragma unroll
            for (int m = 0; m < 4; ++m)
                #pragma unroll
                for (int n = 0; n < 4; ++n)
                    acc[m][n] = __builtin_amdgcn_mfma_f32_16x16x32_bf16(
                        af[m], bfr[n], acc[m][n], 0, 0, 0);
        }
        __syncthreads();
    }

    #pragma unroll
    for (int m = 0; m < 4; ++m) {
        #pragma unroll
        for (int i = 0; i < 4; ++i) {
            const int co = mm0 + wm + m * 16 + l4 * 4 + i;
            if (MODE == 0) {
                float sc, sh; short* dst;
                if (co < CK) {
                    sc = g0[co] * rsqrtf(va0[co] + EPS);
                    sh = be0[co] - mu0[co] * sc;
                    dst = o0 + ((size_t)b * CK + co) * HW;
                } else {
                    int cv = co - CK;
                    sc = g1[cv] * rsqrtf(va1[cv] + EPS);
                    sh = be1[cv] - mu1[cv] * sc;
                    dst = o1 + ((size_t)b * CV + cv) * HW;
                }
                #pragma unroll
                for (int n = 0; n < 4; ++n) {
                    float v = fmaxf(acc[m][n][i] * sc + sh, 0.f);
                    dst[nn0 + wn + n * 16 + l15] = f2b(v);
                }
            } else {
                float sc = g0[co] * rsqrtf(va0[co] + EPS);
                float sh = be0[co] - mu0[co] * sc;
                const float* xr = xres + ((size_t)b * CIN + co) * HW;
                float* orow = of + ((size_t)b * CIN + co) * HW;
                #pragma unroll
                for (int n = 0; n < 4; ++n) {
                    int nidx = nn0 + wn + n * 16 + l15;
                    orow[nidx] = acc[m][n][i] * sc + sh + xr[nidx];
                }
            }
        }
    }
}

// ---------------------------------------------------------------------------
// PSP pool — separable, wave-per-plane; transposed bf16 outputs.
// ---------------------------------------------------------------------------
__global__ __launch_bounds__(256) void psp_pool_kernel(
    const short* __restrict__ qkb, const short* __restrict__ valb,
    short* __restrict__ keyT, short* __restrict__ valueT)
{
    __shared__ float band[4][17][64];
    const int tid = threadIdx.x;
    const int lane = tid & 63, wv = tid >> 6;
    const int c = blockIdx.x * 4 + wv;
    const int b = blockIdx.y;

    const short* src = (c < CK) ? qkb + ((size_t)b * CK + c) * HW
                                : valb + ((size_t)b * CV + (c - CK)) * HW;

    const float NEG = -1e30f;
    float a0 = NEG;
    float b3[3] = {NEG, NEG, NEG};
    float c6[6] = {NEG, NEG, NEG, NEG, NEG, NEG};
    float d8[8] = {NEG, NEG, NEG, NEG, NEG, NEG, NEG, NEG};

    #pragma unroll
    for (int h = 0; h < 64; ++h) {
        float v = b2f(src[h * 64 + lane]);
        a0 = fmaxf(a0, v);
        if (h <= 21)            b3[0] = fmaxf(b3[0], v);
        if (h >= 21 && h <= 42) b3[1] = fmaxf(b3[1], v);
        if (h >= 42)            b3[2] = fmaxf(b3[2], v);
        if (h <= 10)            c6[0] = fmaxf(c6[0], v);
        if (h >= 10 && h <= 21) c6[1] = fmaxf(c6[1], v);
        if (h >= 21 && h <= 31) c6[2] = fmaxf(c6[2], v);
        if (h >= 32 && h <= 42) c6[3] = fmaxf(c6[3], v);
        if (h >= 42 && h <= 53) c6[4] = fmaxf(c6[4], v);
        if (h >= 53)            c6[5] = fmaxf(c6[5], v);
        d8[h >> 3] = fmaxf(d8[h >> 3], v);
    }

    #pragma unroll
    for (int r = 0; r < 3; ++r) band[wv][r][lane] = b3[r];
    #pragma unroll
    for (int r = 0; r < 6; ++r) band[wv][3 + r][lane] = c6[r];
    #pragma unroll
    for (int r = 0; r < 8; ++r) band[wv][9 + r][lane] = d8[r];

    #pragma unroll
    for (int off = 32; off; off >>= 1) a0 = fmaxf(a0, __shfl_xor(a0, off));

    __syncthreads();

    const int isK = (c < CK);
    const int cv = c - CK;

    if (lane == 0) {
        if (isK) keyT[((size_t)b * SP + 0) * CK + c] = f2b(a0);
        else     valueT[((size_t)b * CV + cv) * SP + 0] = f2b(a0);
    }
    {   // s=8: 64 cells
        int i = lane >> 3, j = lane & 7;
        const float* row = band[wv][9 + i];
        float m = row[8 * j];
        #pragma unroll
        for (int k = 1; k < 8; ++k) m = fmaxf(m, row[8 * j + k]);
        int sc = 46 + lane;
        if (isK) keyT[((size_t)b * SP + sc) * CK + c] = f2b(m);
        else     valueT[((size_t)b * CV + cv) * SP + sc] = f2b(m);
    }
    if (lane < 36) {   // s=6
        int i = lane / 6, j = lane - 6 * i;
        int w0 = (j * 64) / 6, w1 = ((j + 1) * 64 + 5) / 6;
        const float* row = band[wv][3 + i];
        float m = NEG;
        for (int k = w0; k < w1; ++k) m = fmaxf(m, row[k]);
        int sc = 10 + lane;
        if (isK) keyT[((size_t)b * SP + sc) * CK + c] = f2b(m);
        else     valueT[((size_t)b * CV + cv) * SP + sc] = f2b(m);
    }
    if (lane < 9) {    // s=3
        int i = lane / 3, j = lane - 3 * i;
        int w0 = (j * 64) / 3, w1 = ((j + 1) * 64 + 2) / 3;
        const float* row = band[wv][i];
        float m = NEG;
        for (int k = w0; k < w1; ++k) m = fmaxf(m, row[k]);
        int sc = 1 + lane;
        if (isK) keyT[((size_t)b * SP + sc) * CK + c] = f2b(m);
        else     valueT[((size_t)b * CV + cv) * SP + sc] = f2b(m);
    }
}

// ---------------------------------------------------------------------------
// Scores MFMA + fused softmax
// ---------------------------------------------------------------------------
__global__ __launch_bounds__(256) void attn_scores_mfma_kernel(
    const short* __restrict__ qkt, const short* __restrict__ keyT,
    short* __restrict__ P)
{
    __shared__ short As[128 * 64];
    __shared__ short Bs[128 * 64];
    __shared__ float red[2][2][128];
    const int b  = blockIdx.y;
    const int m0 = blockIdx.x * 128;
    const int tid = threadIdx.x;
    const int lane = tid & 63, wv = tid >> 6;
    const int wm = (wv >> 1) * 64, wn = (wv & 1) * 64;
    const int l15 = lane & 15, l4 = lane >> 4;

    const short* abase = qkt + ((size_t)b * HW + m0) * CK;
    const short* bbase = keyT + (size_t)b * SP * CK;

    f32x4 acc[4][4] = {};

    for (int kt = 0; kt < CK; kt += 64) {
        stage_tile<CK>(abase, As, tid, kt);
        stage_tile<CK>(bbase, Bs, tid, kt);
        __syncthreads();
        #pragma unroll
        for (int kk = 0; kk < 2; ++kk) {
            bf16x8 af[4], bfr[4];
            #pragma unroll
            for (int m = 0; m < 4; ++m) {
                int row = wm + m * 16 + l15;
                int su = (kk * 4 + l4) ^ (row & 7);
                af[m] = *(const bf16x8*)&As[row * 64 + su * 8];
            }
            #pragma unroll
            for (int n = 0; n < 4; ++n) {
                int row = wn + n * 16 + l15;
                int su = (kk * 4 + l4) ^ (row & 7);
                bfr[n] = *(const bf16x8*)&Bs[row * 64 + su * 8];
            }
            #pragma unroll
            for (int m = 0; m < 4; ++m)
                #pragma unroll
                for (int n = 0; n < 4; ++n)
                    acc[m][n] = __builtin_amdgcn_mfma_f32_16x16x32_bf16(
                        af[m], bfr[n], acc[m][n], 0, 0, 0);
        }
        __syncthreads();
    }

    // ---- fused softmax over s ----
    float pv[4][4][4];   // [m][n][i]
    float rmax[4][4], rsum[4][4];
    #pragma unroll
    for (int m = 0; m < 4; ++m)
        #pragma unroll
        for (int i = 0; i < 4; ++i) {
            float mx = -1e30f;
            #pragma unroll
            for (int n = 0; n < 4; ++n) {
                int s = wn + n * 16 + l15;
                float v = acc[m][n][i] * 0.0625f;
                if (s >= S_) v = -1e30f;
                pv[m][n][i] = v;
                mx = fmaxf(mx, v);
            }
            rmax[m][i] = mx;
        }
    #pragma unroll
    for (int off = 1; off < 16; off <<= 1)
        #pragma unroll
        for (int m = 0; m < 4; ++m)
            #pragma unroll
            for (int i = 0; i < 4; ++i)
                rmax[m][i] = fmaxf(rmax[m][i], __shfl_xor(rmax[m][i], off));
    if (l15 == 0) {
        #pragma unroll
        for (int m = 0; m < 4; ++m)
            #pragma unroll
            for (int i = 0; i < 4; ++i)
                red[0][wv & 1][wm + m * 16 + l4 * 4 + i] = rmax[m][i];
    }
    __syncthreads();
    #pragma unroll
    for (int m = 0; m < 4; ++m)
        #pragma unroll
        for (int i = 0; i < 4; ++i) {
            float gmax = fmaxf(rmax[m][i], red[0][(wv & 1) ^ 1][wm + m * 16 + l4 * 4 + i]);
            float sm = 0.f;
            #pragma unroll
            for (int n = 0; n < 4; ++n) {
                float e = __expf(pv[m][n][i] - gmax);
                pv[m][n][i] = e;
                sm += e;
            }
            rsum[m][i] = sm;
        }
    #pragma unroll
    for (int off = 1; off < 16; off <<= 1)
        #pragma unroll
        for (int m = 0; m < 4; ++m)
            #pragma unroll
            for (int i = 0; i < 4; ++i)
                rsum[m][i] += __shfl_xor(rsum[m][i], off);
    if (l15 == 0) {
        #pragma unroll
        for (int m = 0; m < 4; ++m)
            #pragma unroll
            for (int i = 0; i < 4; ++i)
                red[1][wv & 1][wm + m * 16 + l4 * 4 + i] = rsum[m][i];
    }
    __syncthreads();
    #pragma unroll
    for (int m = 0; m < 4; ++m)
        #pragma unroll
        for (int i = 0; i < 4; ++i) {
            int row = wm + m * 16 + l4 * 4 + i;
            float inv = 1.f / (rsum[m][i] + red[1][(wv & 1) ^ 1][row]);
            short* dst = P + ((size_t)b * HW + m0 + row) * SP + wn + l15;
            #pragma unroll
            for (int n = 0; n < 4; ++n)
                dst[n * 16] = f2b(pv[m][n][i] * inv);
        }
}

// ---------------------------------------------------------------------------
// PV MFMA: Yt[b][n][cv] = sum_s P[n][s] * valueT[cv][s]
// ---------------------------------------------------------------------------
__global__ __launch_bounds__(256) void attn_pv_mfma_kernel(
    const short* __restrict__ P, const short* __restrict__ valueT,
    short* __restrict__ Yt)
{
    __shared__ short As[128 * 64];
    __shared__ short Bs[128 * 64];
    const int b   = blockIdx.z;
    const int m0  = blockIdx.y * 128;    // n-rows
    const int cv0 = blockIdx.x * 128;    // cv cols
    const int tid = threadIdx.x;
    const int lane = tid & 63, wv = tid >> 6;
    const int wm = (wv >> 1) * 64, wn = (wv & 1) * 64;
    const int l15 = lane & 15, l4 = lane >> 4;

    const short* abase = P + ((size_t)b * HW + m0) * SP;
    const short* bbase = valueT + ((size_t)b * CV + cv0) * SP;

    f32x4 acc[4][4] = {};

    for (int kt = 0; kt < SP; kt += 64) {
        stage_tile<SP>(abase, As, tid, kt);
        stage_tile<SP>(bbase, Bs, tid, kt);
        __syncthreads();
        #pragma unroll
        for (int kk = 0; kk < 2; ++kk) {
            bf16x8 af[4], bfr[4];
            #pragma unroll
            for (int m = 0; m < 4; ++m) {
                int row = wm + m * 16 + l15;
                int su = (kk * 4 + l4) ^ (row & 7);
                af[m] = *(const bf16x8*)&As[row * 64 + su * 8];
            }
            #pragma unroll
            for (int n = 0; n < 4; ++n) {
                int row = wn + n * 16 + l15;
                int su = (kk * 4 + l4) ^ (row & 7);
                bfr[n] = *(const bf16x8*)&Bs[row * 64 + su * 8];
            }
            #pragma unroll
            for (int m = 0; m < 4; ++m)
                #pragma unroll
                for (int n = 0; n < 4; ++n)
                    acc[m][n] = __builtin_amdgcn_mfma_f32_16x16x32_bf16(
                        af[m], bfr[n], acc[m][n], 0, 0, 0);
        }
        __syncthreads();
    }

    #pragma unroll
    for (int m = 0; m < 4; ++m)
        #pragma unroll
        for (int i = 0; i < 4; ++i) {
            int row = wm + m * 16 + l4 * 4 + i;
            short* dst = Yt + ((size_t)b * HW + m0 + row) * CV + cv0 + wn + l15;
            #pragma unroll
            for (int n = 0; n < 4; ++n)
                dst[n * 16] = f2b(acc[m][n][i]);
        }
}

// ---------------------------------------------------------------------------
// Launch
// ---------------------------------------------------------------------------
extern "C" void kernel_launch(void* const* d_in, const int* in_sizes, int n_in,
                              void* d_out, int out_size, void* d_ws, size_t ws_size,
                              hipStream_t stream)
{
    const float* x        = (const float*)d_in[0];
    const float* qk_w     = (const float*)d_in[1];
    const float* qk_gamma = (const float*)d_in[2];
    const float* qk_beta  = (const float*)d_in[3];
    const float* qk_mean  = (const float*)d_in[4];
    const float* qk_var   = (const float*)d_in[5];
    const float* v_w      = (const float*)d_in[6];
    const float* v_gamma  = (const float*)d_in[7];
    const float* v_beta   = (const float*)d_in[8];
    const float* v_mean   = (const float*)d_in[9];
    const float* v_var    = (const float*)d_in[10];
    const float* out_w    = (const float*)d_in[11];
    const float* out_gamma= (const float*)d_in[12];
    const float* out_beta = (const float*)d_in[13];
    const float* out_mean = (const float*)d_in[14];
    const float* out_var  = (const float*)d_in[15];

    char* wsb = (char*)d_ws;
    short* xt     = (short*)(wsb);                 // [8][4096][512] bf16 33.5MB
    short* qkt    = xt;                            // aliases xt (dead after gemm<0>)
    short* qkb    = (short*)(wsb + 33554432);      // [8][256][4096] bf16 16.8MB
    short* valb   = (short*)(wsb + 50331648);      // [8][512][4096] bf16 33.5MB
    short* Yt     = valb;                          // aliases valb (dead after pool)
    short* keyT   = (short*)(wsb + 83886080);      // [8][128][256] bf16 0.5MB
    short* valueT = (short*)(wsb + 84410368);      // [8][512][128] bf16 1MB
    short* P      = (short*)(wsb + 85458944);      // [8][4096][128] bf16 8.4MB
    short* wqkv   = (short*)(wsb + 93847552);      // [768][512]
    short* wout   = wqkv + 393216;                 // [512][512]

    transpose_x_kernel<<<dim3(HW / 64, CIN / 64, B_), 256, 0, stream>>>(x, xt);
    convert_w_kernel<<<dim3(640), 256, 0, stream>>>(qk_w, v_w, out_w, wqkv);

    gemm_mfma_kernel<0><<<dim3(HW / 128, 6, B_), 256, 0, stream>>>(
        wqkv, xt, qk_gamma, qk_beta, qk_mean, qk_var,
        v_gamma, v_beta, v_mean, v_var,
        nullptr, qkb, valb, nullptr);

    transpose_qk_kernel<<<dim3(HW / 64, CK / 64, B_), 256, 0, stream>>>(qkb, qkt);

    psp_pool_kernel<<<dim3((CK + CV) / 4, B_), 256, 0, stream>>>(qkb, valb, keyT, valueT);

    attn_scores_mfma_kernel<<<dim3(HW / 128, B_), 256, 0, stream>>>(qkt, keyT, P);

    attn_pv_mfma_kernel<<<dim3(CV / 128, HW / 128, B_), 256, 0, stream>>>(P, valueT, Yt);

    gemm_mfma_kernel<1><<<dim3(HW / 128, 4, B_), 256, 0, stream>>>(
        wout, Yt, out_gamma, out_beta, out_mean, out_var,
        nullptr, nullptr, nullptr, nullptr,
        x, nullptr, nullptr, (float*)d_out);
}

// Round 9
// 269.848 us; speedup vs baseline: 4.1150x; 1.0106x over previous
//
#include <hip/hip_runtime.h>
#include <math.h>

#define B_    8
#define CIN   512
#define CK    256
#define CV    512
#define HW    4096
#define S_    110
#define SP    128          // padded S for MFMA
#define EPS   1e-5f

typedef __attribute__((ext_vector_type(8))) short bf16x8;
typedef __attribute__((ext_vector_type(4))) short bf16x4;
typedef __attribute__((ext_vector_type(4))) float f32x4;

__device__ __forceinline__ float b2f(short s) {
    unsigned int u = ((unsigned int)(unsigned short)s) << 16;
    union { unsigned int u; float f; } c; c.u = u; return c.f;
}
__device__ __forceinline__ short f2b(float f) {
    union { float f; unsigned int u; } c; c.f = f;
    unsigned int r = (c.u + 0x7FFFu + ((c.u >> 16) & 1u)) >> 16;   // RNE
    return (short)r;
}

// async global->LDS, 16B per lane, wave-linear LDS dest
__device__ __forceinline__ void gload_lds16(const short* g, short* l) {
    __builtin_amdgcn_global_load_lds(
        (const __attribute__((address_space(1))) void*)g,
        (__attribute__((address_space(3))) void*)l,
        16, 0, 0);
}

// Stage a 128-row x 64-short K-tile (XOR-swizzled) via global_load_lds.
// LDS unit u (row=u>>3, slot=u&7) receives global k-unit (slot ^ (row&7)).
template<int STRIDE>
__device__ __forceinline__ void stage_tile(
    const short* __restrict__ base, short* lds, int tid, int kt)
{
    const int wv = tid >> 6, lane = tid & 63;
    #pragma unroll
    for (int q = 0; q < 4; ++q) {
        const int u = q * 256 + wv * 64 + lane;      // 16B-unit index [0,1024)
        const int row = u >> 3;
        const int kunit = (u & 7) ^ (row & 7);
        gload_lds16(base + (size_t)row * STRIDE + kt + kunit * 8,
                    lds + (q * 256 + wv * 64) * 8);  // wave-uniform base
    }
}

// One BK=64 MFMA step (2 sub-K of 32) on a staged tile pair.
__device__ __forceinline__ void mfma_step(
    const short* As, const short* Bs, int wm, int wn, int l15, int l4,
    f32x4 acc[4][4])
{
    #pragma unroll
    for (int kk = 0; kk < 2; ++kk) {
        bf16x8 af[4], bfr[4];
        #pragma unroll
        for (int m = 0; m < 4; ++m) {
            int row = wm + m * 16 + l15;
            int su = (kk * 4 + l4) ^ (row & 7);
            af[m] = *(const bf16x8*)&As[row * 64 + su * 8];
        }
        #pragma unroll
        for (int n = 0; n < 4; ++n) {
            int row = wn + n * 16 + l15;
            int su = (kk * 4 + l4) ^ (row & 7);
            bfr[n] = *(const bf16x8*)&Bs[row * 64 + su * 8];
        }
        #pragma unroll
        for (int m = 0; m < 4; ++m)
            #pragma unroll
            for (int n = 0; n < 4; ++n)
                acc[m][n] = __builtin_amdgcn_mfma_f32_16x16x32_bf16(
                    af[m], bfr[n], acc[m][n], 0, 0, 0);
    }
}

// 2-phase double-buffered K-loop: issue next-tile stage BEFORE computing
// current tile; ONE barrier per tile. NK must be even.
template<int NK, int SA, int SB>
__device__ __forceinline__ void gemm_loop(
    const short* __restrict__ abase, const short* __restrict__ bbase,
    short* As0, short* As1, short* Bs0, short* Bs1,
    int tid, int wm, int wn, int l15, int l4, f32x4 acc[4][4])
{
    stage_tile<SA>(abase, As0, tid, 0);
    stage_tile<SB>(bbase, Bs0, tid, 0);
    __syncthreads();
    #pragma unroll
    for (int t = 0; t < NK; t += 2) {
        if (t + 1 < NK) {
            stage_tile<SA>(abase, As1, tid, (t + 1) * 64);
            stage_tile<SB>(bbase, Bs1, tid, (t + 1) * 64);
        }
        mfma_step(As0, Bs0, wm, wn, l15, l4, acc);
        __syncthreads();
        if (t + 2 < NK) {
            stage_tile<SA>(abase, As0, tid, (t + 2) * 64);
            stage_tile<SB>(bbase, Bs0, tid, (t + 2) * 64);
        }
        mfma_step(As1, Bs1, wm, wn, l15, l4, acc);
        __syncthreads();
    }
}

// ---------------------------------------------------------------------------
// x [b][c][n] fp32 -> xt [b][n][c] bf16
// ---------------------------------------------------------------------------
__global__ __launch_bounds__(256) void transpose_x_kernel(
    const float* __restrict__ x, short* __restrict__ xt)
{
    __shared__ short t[64][65];
    const int b = blockIdx.z, c0 = blockIdx.y * 64, n0 = blockIdx.x * 64;
    const int tid = threadIdx.x;
    const float* src = x + ((size_t)b * CIN + c0) * HW + n0;
    const int j = tid & 63, i0 = tid >> 6;
    #pragma unroll
    for (int q = 0; q < 16; ++q) {
        int i = i0 * 16 + q;
        t[i][j] = f2b(src[(size_t)i * HW + j]);
    }
    __syncthreads();
    short* dst = xt + ((size_t)b * HW + n0) * CIN + c0;
    const int hh = tid & 31, jb = tid >> 5;
    #pragma unroll
    for (int q = 0; q < 8; ++q) {
        int jj = jb * 8 + q;
        short2 v; v.x = t[2 * hh][jj]; v.y = t[2 * hh + 1][jj];
        *(short2*)(dst + (size_t)jj * CIN + 2 * hh) = v;
    }
}

// ---------------------------------------------------------------------------
// qkb [b][c][n] bf16 -> qkt [b][n][c] bf16
// ---------------------------------------------------------------------------
__global__ __launch_bounds__(256) void transpose_qk_kernel(
    const short* __restrict__ qkb, short* __restrict__ qkt)
{
    __shared__ short t[64][65];
    const int b = blockIdx.z, c0 = blockIdx.y * 64, n0 = blockIdx.x * 64;
    const int tid = threadIdx.x;
    const short* src = qkb + ((size_t)b * CK + c0) * HW + n0;
    const int j = tid & 63, i0 = tid >> 6;
    #pragma unroll
    for (int q = 0; q < 16; ++q) {
        int i = i0 * 16 + q;
        t[i][j] = src[(size_t)i * HW + j];
    }
    __syncthreads();
    short* dst = qkt + ((size_t)b * HW + n0) * CK + c0;
    const int hh = tid & 31, jb = tid >> 5;
    #pragma unroll
    for (int q = 0; q < 8; ++q) {
        int jj = jb * 8 + q;
        short2 v; v.x = t[2 * hh][jj]; v.y = t[2 * hh + 1][jj];
        *(short2*)(dst + (size_t)jj * CK + 2 * hh) = v;
    }
}

// ---------------------------------------------------------------------------
// weights fp32 -> bf16
// ---------------------------------------------------------------------------
__global__ __launch_bounds__(256) void convert_w_kernel(
    const float* __restrict__ qk_w, const float* __restrict__ v_w,
    const float* __restrict__ out_w, short* __restrict__ wb)
{
    const int id4 = (blockIdx.x * 256 + threadIdx.x) * 4;
    #pragma unroll
    for (int r = 0; r < 4; ++r) {
        int id = id4 + r;
        float f = (id < 131072) ? qk_w[id]
                : (id < 393216) ? v_w[id - 131072]
                                : out_w[id - 393216];
        wb[id] = f2b(f);
    }
}

// ---------------------------------------------------------------------------
// MFMA GEMM (convs): C[co][n] = sum_k W[co][k] * Bt[n][k]
// ---------------------------------------------------------------------------
template<int MODE>
__global__ __launch_bounds__(256) void gemm_mfma_kernel(
    const short* __restrict__ W, const short* __restrict__ Bt,
    const float* __restrict__ g0, const float* __restrict__ be0,
    const float* __restrict__ mu0, const float* __restrict__ va0,
    const float* __restrict__ g1, const float* __restrict__ be1,
    const float* __restrict__ mu1, const float* __restrict__ va1,
    const float* __restrict__ xres,
    short* __restrict__ o0, short* __restrict__ o1,
    float* __restrict__ of)
{
    __shared__ short As[2][128 * 64];
    __shared__ short Bs[2][128 * 64];
    const int b   = blockIdx.z;
    const int mm0 = blockIdx.y * 128, nn0 = blockIdx.x * 128;
    const int tid = threadIdx.x;
    const int lane = tid & 63, wv = tid >> 6;
    const int wm = (wv >> 1) * 64, wn = (wv & 1) * 64;
    const int l15 = lane & 15, l4 = lane >> 4;

    const short* wbase = W + (size_t)mm0 * 512;
    const short* xbase = Bt + ((size_t)b * HW + nn0) * 512;

    f32x4 acc[4][4] = {};
    gemm_loop<8, 512, 512>(wbase, xbase, As[0], As[1], Bs[0], Bs[1],
                           tid, wm, wn, l15, l4, acc);

    #pragma unroll
    for (int m = 0; m < 4; ++m) {
        #pragma unroll
        for (int i = 0; i < 4; ++i) {
            const int co = mm0 + wm + m * 16 + l4 * 4 + i;
            if (MODE == 0) {
                float sc, sh; short* dst;
                if (co < CK) {
                    sc = g0[co] * rsqrtf(va0[co] + EPS);
                    sh = be0[co] - mu0[co] * sc;
                    dst = o0 + ((size_t)b * CK + co) * HW;
                } else {
                    int cv = co - CK;
                    sc = g1[cv] * rsqrtf(va1[cv] + EPS);
                    sh = be1[cv] - mu1[cv] * sc;
                    dst = o1 + ((size_t)b * CV + cv) * HW;
                }
                #pragma unroll
                for (int n = 0; n < 4; ++n) {
                    float v = fmaxf(acc[m][n][i] * sc + sh, 0.f);
                    dst[nn0 + wn + n * 16 + l15] = f2b(v);
                }
            } else {
                float sc = g0[co] * rsqrtf(va0[co] + EPS);
                float sh = be0[co] - mu0[co] * sc;
                const float* xr = xres + ((size_t)b * CIN + co) * HW;
                float* orow = of + ((size_t)b * CIN + co) * HW;
                #pragma unroll
                for (int n = 0; n < 4; ++n) {
                    int nidx = nn0 + wn + n * 16 + l15;
                    orow[nidx] = acc[m][n][i] * sc + sh + xr[nidx];
                }
            }
        }
    }
}

// ---------------------------------------------------------------------------
// PSP pool — separable, wave-per-plane; transposed bf16 outputs.
// ---------------------------------------------------------------------------
__global__ __launch_bounds__(256) void psp_pool_kernel(
    const short* __restrict__ qkb, const short* __restrict__ valb,
    short* __restrict__ keyT, short* __restrict__ valueT)
{
    __shared__ float band[4][17][64];
    const int tid = threadIdx.x;
    const int lane = tid & 63, wv = tid >> 6;
    const int c = blockIdx.x * 4 + wv;
    const int b = blockIdx.y;

    const short* src = (c < CK) ? qkb + ((size_t)b * CK + c) * HW
                                : valb + ((size_t)b * CV + (c - CK)) * HW;

    const float NEG = -1e30f;
    float a0 = NEG;
    float b3[3] = {NEG, NEG, NEG};
    float c6[6] = {NEG, NEG, NEG, NEG, NEG, NEG};
    float d8[8] = {NEG, NEG, NEG, NEG, NEG, NEG, NEG, NEG};

    #pragma unroll
    for (int h = 0; h < 64; ++h) {
        float v = b2f(src[h * 64 + lane]);
        a0 = fmaxf(a0, v);
        if (h <= 21)            b3[0] = fmaxf(b3[0], v);
        if (h >= 21 && h <= 42) b3[1] = fmaxf(b3[1], v);
        if (h >= 42)            b3[2] = fmaxf(b3[2], v);
        if (h <= 10)            c6[0] = fmaxf(c6[0], v);
        if (h >= 10 && h <= 21) c6[1] = fmaxf(c6[1], v);
        if (h >= 21 && h <= 31) c6[2] = fmaxf(c6[2], v);
        if (h >= 32 && h <= 42) c6[3] = fmaxf(c6[3], v);
        if (h >= 42 && h <= 53) c6[4] = fmaxf(c6[4], v);
        if (h >= 53)            c6[5] = fmaxf(c6[5], v);
        d8[h >> 3] = fmaxf(d8[h >> 3], v);
    }

    #pragma unroll
    for (int r = 0; r < 3; ++r) band[wv][r][lane] = b3[r];
    #pragma unroll
    for (int r = 0; r < 6; ++r) band[wv][3 + r][lane] = c6[r];
    #pragma unroll
    for (int r = 0; r < 8; ++r) band[wv][9 + r][lane] = d8[r];

    #pragma unroll
    for (int off = 32; off; off >>= 1) a0 = fmaxf(a0, __shfl_xor(a0, off));

    __syncthreads();

    const int isK = (c < CK);
    const int cv = c - CK;

    if (lane == 0) {
        if (isK) keyT[((size_t)b * SP + 0) * CK + c] = f2b(a0);
        else     valueT[((size_t)b * CV + cv) * SP + 0] = f2b(a0);
    }
    {   // s=8: 64 cells
        int i = lane >> 3, j = lane & 7;
        const float* row = band[wv][9 + i];
        float m = row[8 * j];
        #pragma unroll
        for (int k = 1; k < 8; ++k) m = fmaxf(m, row[8 * j + k]);
        int sc = 46 + lane;
        if (isK) keyT[((size_t)b * SP + sc) * CK + c] = f2b(m);
        else     valueT[((size_t)b * CV + cv) * SP + sc] = f2b(m);
    }
    if (lane < 36) {   // s=6
        int i = lane / 6, j = lane - 6 * i;
        int w0 = (j * 64) / 6, w1 = ((j + 1) * 64 + 5) / 6;
        const float* row = band[wv][3 + i];
        float m = NEG;
        for (int k = w0; k < w1; ++k) m = fmaxf(m, row[k]);
        int sc = 10 + lane;
        if (isK) keyT[((size_t)b * SP + sc) * CK + c] = f2b(m);
        else     valueT[((size_t)b * CV + cv) * SP + sc] = f2b(m);
    }
    if (lane < 9) {    // s=3
        int i = lane / 3, j = lane - 3 * i;
        int w0 = (j * 64) / 3, w1 = ((j + 1) * 64 + 2) / 3;
        const float* row = band[wv][i];
        float m = NEG;
        for (int k = w0; k < w1; ++k) m = fmaxf(m, row[k]);
        int sc = 1 + lane;
        if (isK) keyT[((size_t)b * SP + sc) * CK + c] = f2b(m);
        else     valueT[((size_t)b * CV + cv) * SP + sc] = f2b(m);
    }
}

// ---------------------------------------------------------------------------
// Scores MFMA + fused softmax
// ---------------------------------------------------------------------------
__global__ __launch_bounds__(256) void attn_scores_mfma_kernel(
    const short* __restrict__ qkt, const short* __restrict__ keyT,
    short* __restrict__ P)
{
    __shared__ short As[2][128 * 64];
    __shared__ short Bs[2][128 * 64];
    __shared__ float red[2][2][128];
    const int b  = blockIdx.y;
    const int m0 = blockIdx.x * 128;
    const int tid = threadIdx.x;
    const int lane = tid & 63, wv = tid >> 6;
    const int wm = (wv >> 1) * 64, wn = (wv & 1) * 64;
    const int l15 = lane & 15, l4 = lane >> 4;

    const short* abase = qkt + ((size_t)b * HW + m0) * CK;
    const short* bbase = keyT + (size_t)b * SP * CK;

    f32x4 acc[4][4] = {};
    gemm_loop<4, CK, CK>(abase, bbase, As[0], As[1], Bs[0], Bs[1],
                         tid, wm, wn, l15, l4, acc);

    // ---- fused softmax over s ----
    float pv[4][4][4];   // [m][n][i]
    float rmax[4][4], rsum[4][4];
    #pragma unroll
    for (int m = 0; m < 4; ++m)
        #pragma unroll
        for (int i = 0; i < 4; ++i) {
            float mx = -1e30f;
            #pragma unroll
            for (int n = 0; n < 4; ++n) {
                int s = wn + n * 16 + l15;
                float v = acc[m][n][i] * 0.0625f;
                if (s >= S_) v = -1e30f;
                pv[m][n][i] = v;
                mx = fmaxf(mx, v);
            }
            rmax[m][i] = mx;
        }
    #pragma unroll
    for (int off = 1; off < 16; off <<= 1)
        #pragma unroll
        for (int m = 0; m < 4; ++m)
            #pragma unroll
            for (int i = 0; i < 4; ++i)
                rmax[m][i] = fmaxf(rmax[m][i], __shfl_xor(rmax[m][i], off));
    if (l15 == 0) {
        #pragma unroll
        for (int m = 0; m < 4; ++m)
            #pragma unroll
            for (int i = 0; i < 4; ++i)
                red[0][wv & 1][wm + m * 16 + l4 * 4 + i] = rmax[m][i];
    }
    __syncthreads();
    #pragma unroll
    for (int m = 0; m < 4; ++m)
        #pragma unroll
        for (int i = 0; i < 4; ++i) {
            float gmax = fmaxf(rmax[m][i], red[0][(wv & 1) ^ 1][wm + m * 16 + l4 * 4 + i]);
            float sm = 0.f;
            #pragma unroll
            for (int n = 0; n < 4; ++n) {
                float e = __expf(pv[m][n][i] - gmax);
                pv[m][n][i] = e;
                sm += e;
            }
            rsum[m][i] = sm;
        }
    #pragma unroll
    for (int off = 1; off < 16; off <<= 1)
        #pragma unroll
        for (int m = 0; m < 4; ++m)
            #pragma unroll
            for (int i = 0; i < 4; ++i)
                rsum[m][i] += __shfl_xor(rsum[m][i], off);
    if (l15 == 0) {
        #pragma unroll
        for (int m = 0; m < 4; ++m)
            #pragma unroll
            for (int i = 0; i < 4; ++i)
                red[1][wv & 1][wm + m * 16 + l4 * 4 + i] = rsum[m][i];
    }
    __syncthreads();
    #pragma unroll
    for (int m = 0; m < 4; ++m)
        #pragma unroll
        for (int i = 0; i < 4; ++i) {
            int row = wm + m * 16 + l4 * 4 + i;
            float inv = 1.f / (rsum[m][i] + red[1][(wv & 1) ^ 1][row]);
            short* dst = P + ((size_t)b * HW + m0 + row) * SP + wn + l15;
            #pragma unroll
            for (int n = 0; n < 4; ++n)
                dst[n * 16] = f2b(pv[m][n][i] * inv);
        }
}

// ---------------------------------------------------------------------------
// PV MFMA: Yt[b][n][cv] = sum_s P[n][s] * valueT[cv][s]
// ---------------------------------------------------------------------------
__global__ __launch_bounds__(256) void attn_pv_mfma_kernel(
    const short* __restrict__ P, const short* __restrict__ valueT,
    short* __restrict__ Yt)
{
    __shared__ short As[2][128 * 64];
    __shared__ short Bs[2][128 * 64];
    const int b   = blockIdx.z;
    const int m0  = blockIdx.y * 128;    // n-rows
    const int cv0 = blockIdx.x * 128;    // cv cols
    const int tid = threadIdx.x;
    const int lane = tid & 63, wv = tid >> 6;
    const int wm = (wv >> 1) * 64, wn = (wv & 1) * 64;
    const int l15 = lane & 15, l4 = lane >> 4;

    const short* abase = P + ((size_t)b * HW + m0) * SP;
    const short* bbase = valueT + ((size_t)b * CV + cv0) * SP;

    f32x4 acc[4][4] = {};
    gemm_loop<2, SP, SP>(abase, bbase, As[0], As[1], Bs[0], Bs[1],
                         tid, wm, wn, l15, l4, acc);

    #pragma unroll
    for (int m = 0; m < 4; ++m)
        #pragma unroll
        for (int i = 0; i < 4; ++i) {
            int row = wm + m * 16 + l4 * 4 + i;
            short* dst = Yt + ((size_t)b * HW + m0 + row) * CV + cv0 + wn + l15;
            #pragma unroll
            for (int n = 0; n < 4; ++n)
                dst[n * 16] = f2b(acc[m][n][i]);
        }
}

// ---------------------------------------------------------------------------
// Launch
// ---------------------------------------------------------------------------
extern "C" void kernel_launch(void* const* d_in, const int* in_sizes, int n_in,
                              void* d_out, int out_size, void* d_ws, size_t ws_size,
                              hipStream_t stream)
{
    const float* x        = (const float*)d_in[0];
    const float* qk_w     = (const float*)d_in[1];
    const float* qk_gamma = (const float*)d_in[2];
    const float* qk_beta  = (const float*)d_in[3];
    const float* qk_mean  = (const float*)d_in[4];
    const float* qk_var   = (const float*)d_in[5];
    const float* v_w      = (const float*)d_in[6];
    const float* v_gamma  = (const float*)d_in[7];
    const float* v_beta   = (const float*)d_in[8];
    const float* v_mean   = (const float*)d_in[9];
    const float* v_var    = (const float*)d_in[10];
    const float* out_w    = (const float*)d_in[11];
    const float* out_gamma= (const float*)d_in[12];
    const float* out_beta = (const float*)d_in[13];
    const float* out_mean = (const float*)d_in[14];
    const float* out_var  = (const float*)d_in[15];

    char* wsb = (char*)d_ws;
    short* xt     = (short*)(wsb);                 // [8][4096][512] bf16 33.5MB
    short* qkt    = xt;                            // aliases xt (dead after gemm<0>)
    short* qkb    = (short*)(wsb + 33554432);      // [8][256][4096] bf16 16.8MB
    short* valb   = (short*)(wsb + 50331648);      // [8][512][4096] bf16 33.5MB
    short* Yt     = valb;                          // aliases valb (dead after pool)
    short* keyT   = (short*)(wsb + 83886080);      // [8][128][256] bf16 0.5MB
    short* valueT = (short*)(wsb + 84410368);      // [8][512][128] bf16 1MB
    short* P      = (short*)(wsb + 85458944);      // [8][4096][128] bf16 8.4MB
    short* wqkv   = (short*)(wsb + 93847552);      // [768][512]
    short* wout   = wqkv + 393216;                 // [512][512]

    transpose_x_kernel<<<dim3(HW / 64, CIN / 64, B_), 256, 0, stream>>>(x, xt);
    convert_w_kernel<<<dim3(640), 256, 0, stream>>>(qk_w, v_w, out_w, wqkv);

    gemm_mfma_kernel<0><<<dim3(HW / 128, 6, B_), 256, 0, stream>>>(
        wqkv, xt, qk_gamma, qk_beta, qk_mean, qk_var,
        v_gamma, v_beta, v_mean, v_var,
        nullptr, qkb, valb, nullptr);

    transpose_qk_kernel<<<dim3(HW / 64, CK / 64, B_), 256, 0, stream>>>(qkb, qkt);

    psp_pool_kernel<<<dim3((CK + CV) / 4, B_), 256, 0, stream>>>(qkb, valb, keyT, valueT);

    attn_scores_mfma_kernel<<<dim3(HW / 128, B_), 256, 0, stream>>>(qkt, keyT, P);

    attn_pv_mfma_kernel<<<dim3(CV / 128, HW / 128, B_), 256, 0, stream>>>(P, valueT, Yt);

    gemm_mfma_kernel<1><<<dim3(HW / 128, 4, B_), 256, 0, stream>>>(
        wout, Yt, out_gamma, out_beta, out_mean, out_var,
        nullptr, nullptr, nullptr, nullptr,
        x, nullptr, nullptr, (float*)d_out);
}

// Round 10
// 265.443 us; speedup vs baseline: 4.1833x; 1.0166x over previous
//
#include <hip/hip_runtime.h>
#include <math.h>

#define B_    8
#define CIN   512
#define CK    256
#define CV    512
#define HW    4096
#define S_    110
#define SP    128          // padded S for MFMA
#define EPS   1e-5f

typedef __attribute__((ext_vector_type(8))) short bf16x8;
typedef __attribute__((ext_vector_type(4))) short bf16x4;
typedef __attribute__((ext_vector_type(4))) float f32x4;

__device__ __forceinline__ float b2f(short s) {
    unsigned int u = ((unsigned int)(unsigned short)s) << 16;
    union { unsigned int u; float f; } c; c.u = u; return c.f;
}
__device__ __forceinline__ short f2b(float f) {
    union { float f; unsigned int u; } c; c.f = f;
    unsigned int r = (c.u + 0x7FFFu + ((c.u >> 16) & 1u)) >> 16;   // RNE
    return (short)r;
}

// async global->LDS, 16B per lane, wave-linear LDS dest
__device__ __forceinline__ void gload_lds16(const short* g, short* l) {
    __builtin_amdgcn_global_load_lds(
        (const __attribute__((address_space(1))) void*)g,
        (__attribute__((address_space(3))) void*)l,
        16, 0, 0);
}

// Stage a 128-row x 64-short K-tile (XOR-swizzled) via global_load_lds.
// LDS unit u (row=u>>3, slot=u&7) receives global k-unit (slot ^ (row&7)).
template<int STRIDE>
__device__ __forceinline__ void stage_tile(
    const short* __restrict__ base, short* lds, int tid, int kt)
{
    const int wv = tid >> 6, lane = tid & 63;
    #pragma unroll
    for (int q = 0; q < 4; ++q) {
        const int u = q * 256 + wv * 64 + lane;      // 16B-unit index [0,1024)
        const int row = u >> 3;
        const int kunit = (u & 7) ^ (row & 7);
        gload_lds16(base + (size_t)row * STRIDE + kt + kunit * 8,
                    lds + (q * 256 + wv * 64) * 8);  // wave-uniform base
    }
}

// One BK=64 MFMA step (2 sub-K of 32) on a staged tile pair.
__device__ __forceinline__ void mfma_step(
    const short* As, const short* Bs, int wm, int wn, int l15, int l4,
    f32x4 acc[4][4])
{
    #pragma unroll
    for (int kk = 0; kk < 2; ++kk) {
        bf16x8 af[4], bfr[4];
        #pragma unroll
        for (int m = 0; m < 4; ++m) {
            int row = wm + m * 16 + l15;
            int su = (kk * 4 + l4) ^ (row & 7);
            af[m] = *(const bf16x8*)&As[row * 64 + su * 8];
        }
        #pragma unroll
        for (int n = 0; n < 4; ++n) {
            int row = wn + n * 16 + l15;
            int su = (kk * 4 + l4) ^ (row & 7);
            bfr[n] = *(const bf16x8*)&Bs[row * 64 + su * 8];
        }
        #pragma unroll
        for (int m = 0; m < 4; ++m)
            #pragma unroll
            for (int n = 0; n < 4; ++n)
                acc[m][n] = __builtin_amdgcn_mfma_f32_16x16x32_bf16(
                    af[m], bfr[n], acc[m][n], 0, 0, 0);
    }
}

// 2-phase double-buffered K-loop: issue next-tile stage BEFORE computing
// current tile; ONE barrier per tile. NK must be even.
template<int NK, int SA, int SB>
__device__ __forceinline__ void gemm_loop(
    const short* __restrict__ abase, const short* __restrict__ bbase,
    short* As0, short* As1, short* Bs0, short* Bs1,
    int tid, int wm, int wn, int l15, int l4, f32x4 acc[4][4])
{
    stage_tile<SA>(abase, As0, tid, 0);
    stage_tile<SB>(bbase, Bs0, tid, 0);
    __syncthreads();
    #pragma unroll
    for (int t = 0; t < NK; t += 2) {
        if (t + 1 < NK) {
            stage_tile<SA>(abase, As1, tid, (t + 1) * 64);
            stage_tile<SB>(bbase, Bs1, tid, (t + 1) * 64);
        }
        mfma_step(As0, Bs0, wm, wn, l15, l4, acc);
        __syncthreads();
        if (t + 2 < NK) {
            stage_tile<SA>(abase, As0, tid, (t + 2) * 64);
            stage_tile<SB>(bbase, Bs0, tid, (t + 2) * 64);
        }
        mfma_step(As1, Bs1, wm, wn, l15, l4, acc);
        __syncthreads();
    }
}

// ---------------------------------------------------------------------------
// x [b][c][n] fp32 -> xt [b][n][c] bf16
// ---------------------------------------------------------------------------
__global__ __launch_bounds__(256) void transpose_x_kernel(
    const float* __restrict__ x, short* __restrict__ xt)
{
    __shared__ short t[64][65];
    const int b = blockIdx.z, c0 = blockIdx.y * 64, n0 = blockIdx.x * 64;
    const int tid = threadIdx.x;
    const float* src = x + ((size_t)b * CIN + c0) * HW + n0;
    const int j = tid & 63, i0 = tid >> 6;
    #pragma unroll
    for (int q = 0; q < 16; ++q) {
        int i = i0 * 16 + q;
        t[i][j] = f2b(src[(size_t)i * HW + j]);
    }
    __syncthreads();
    short* dst = xt + ((size_t)b * HW + n0) * CIN + c0;
    const int hh = tid & 31, jb = tid >> 5;
    #pragma unroll
    for (int q = 0; q < 8; ++q) {
        int jj = jb * 8 + q;
        short2 v; v.x = t[2 * hh][jj]; v.y = t[2 * hh + 1][jj];
        *(short2*)(dst + (size_t)jj * CIN + 2 * hh) = v;
    }
}

// ---------------------------------------------------------------------------
// qkb [b][c][n] bf16 -> qkt [b][n][c] bf16
// ---------------------------------------------------------------------------
__global__ __launch_bounds__(256) void transpose_qk_kernel(
    const short* __restrict__ qkb, short* __restrict__ qkt)
{
    __shared__ short t[64][65];
    const int b = blockIdx.z, c0 = blockIdx.y * 64, n0 = blockIdx.x * 64;
    const int tid = threadIdx.x;
    const short* src = qkb + ((size_t)b * CK + c0) * HW + n0;
    const int j = tid & 63, i0 = tid >> 6;
    #pragma unroll
    for (int q = 0; q < 16; ++q) {
        int i = i0 * 16 + q;
        t[i][j] = src[(size_t)i * HW + j];
    }
    __syncthreads();
    short* dst = qkt + ((size_t)b * HW + n0) * CK + c0;
    const int hh = tid & 31, jb = tid >> 5;
    #pragma unroll
    for (int q = 0; q < 8; ++q) {
        int jj = jb * 8 + q;
        short2 v; v.x = t[2 * hh][jj]; v.y = t[2 * hh + 1][jj];
        *(short2*)(dst + (size_t)jj * CK + 2 * hh) = v;
    }
}

// ---------------------------------------------------------------------------
// weights fp32 -> bf16
// ---------------------------------------------------------------------------
__global__ __launch_bounds__(256) void convert_w_kernel(
    const float* __restrict__ qk_w, const float* __restrict__ v_w,
    const float* __restrict__ out_w, short* __restrict__ wb)
{
    const int id4 = (blockIdx.x * 256 + threadIdx.x) * 4;
    #pragma unroll
    for (int r = 0; r < 4; ++r) {
        int id = id4 + r;
        float f = (id < 131072) ? qk_w[id]
                : (id < 393216) ? v_w[id - 131072]
                                : out_w[id - 393216];
        wb[id] = f2b(f);
    }
}

// ---------------------------------------------------------------------------
// MFMA GEMM (convs): C[co][n] = sum_k W[co][k] * Bt[n][k]
// ---------------------------------------------------------------------------
template<int MODE>
__global__ __launch_bounds__(256) void gemm_mfma_kernel(
    const short* __restrict__ W, const short* __restrict__ Bt,
    const float* __restrict__ g0, const float* __restrict__ be0,
    const float* __restrict__ mu0, const float* __restrict__ va0,
    const float* __restrict__ g1, const float* __restrict__ be1,
    const float* __restrict__ mu1, const float* __restrict__ va1,
    const float* __restrict__ xres,
    short* __restrict__ o0, short* __restrict__ o1,
    float* __restrict__ of)
{
    __shared__ short As[2][128 * 64];
    __shared__ short Bs[2][128 * 64];
    const int b   = blockIdx.z;
    const int mm0 = blockIdx.y * 128, nn0 = blockIdx.x * 128;
    const int tid = threadIdx.x;
    const int lane = tid & 63, wv = tid >> 6;
    const int wm = (wv >> 1) * 64, wn = (wv & 1) * 64;
    const int l15 = lane & 15, l4 = lane >> 4;

    const short* wbase = W + (size_t)mm0 * 512;
    const short* xbase = Bt + ((size_t)b * HW + nn0) * 512;

    f32x4 acc[4][4] = {};
    gemm_loop<8, 512, 512>(wbase, xbase, As[0], As[1], Bs[0], Bs[1],
                           tid, wm, wn, l15, l4, acc);

    #pragma unroll
    for (int m = 0; m < 4; ++m) {
        #pragma unroll
        for (int i = 0; i < 4; ++i) {
            const int co = mm0 + wm + m * 16 + l4 * 4 + i;
            if (MODE == 0) {
                float sc, sh; short* dst;
                if (co < CK) {
                    sc = g0[co] * rsqrtf(va0[co] + EPS);
                    sh = be0[co] - mu0[co] * sc;
                    dst = o0 + ((size_t)b * CK + co) * HW;
                } else {
                    int cv = co - CK;
                    sc = g1[cv] * rsqrtf(va1[cv] + EPS);
                    sh = be1[cv] - mu1[cv] * sc;
                    dst = o1 + ((size_t)b * CV + cv) * HW;
                }
                #pragma unroll
                for (int n = 0; n < 4; ++n) {
                    float v = fmaxf(acc[m][n][i] * sc + sh, 0.f);
                    dst[nn0 + wn + n * 16 + l15] = f2b(v);
                }
            } else {
                float sc = g0[co] * rsqrtf(va0[co] + EPS);
                float sh = be0[co] - mu0[co] * sc;
                const float* xr = xres + ((size_t)b * CIN + co) * HW;
                float* orow = of + ((size_t)b * CIN + co) * HW;
                #pragma unroll
                for (int n = 0; n < 4; ++n) {
                    int nidx = nn0 + wn + n * 16 + l15;
                    orow[nidx] = acc[m][n][i] * sc + sh + xr[nidx];
                }
            }
        }
    }
}

// ---------------------------------------------------------------------------
// PSP pool — separable, wave-per-plane; transposed bf16 outputs.
// ---------------------------------------------------------------------------
__global__ __launch_bounds__(256) void psp_pool_kernel(
    const short* __restrict__ qkb, const short* __restrict__ valb,
    short* __restrict__ keyT, short* __restrict__ valueT)
{
    __shared__ float band[4][17][64];
    const int tid = threadIdx.x;
    const int lane = tid & 63, wv = tid >> 6;
    const int c = blockIdx.x * 4 + wv;
    const int b = blockIdx.y;

    const short* src = (c < CK) ? qkb + ((size_t)b * CK + c) * HW
                                : valb + ((size_t)b * CV + (c - CK)) * HW;

    const float NEG = -1e30f;
    float a0 = NEG;
    float b3[3] = {NEG, NEG, NEG};
    float c6[6] = {NEG, NEG, NEG, NEG, NEG, NEG};
    float d8[8] = {NEG, NEG, NEG, NEG, NEG, NEG, NEG, NEG};

    #pragma unroll
    for (int h = 0; h < 64; ++h) {
        float v = b2f(src[h * 64 + lane]);
        a0 = fmaxf(a0, v);
        if (h <= 21)            b3[0] = fmaxf(b3[0], v);
        if (h >= 21 && h <= 42) b3[1] = fmaxf(b3[1], v);
        if (h >= 42)            b3[2] = fmaxf(b3[2], v);
        if (h <= 10)            c6[0] = fmaxf(c6[0], v);
        if (h >= 10 && h <= 21) c6[1] = fmaxf(c6[1], v);
        if (h >= 21 && h <= 31) c6[2] = fmaxf(c6[2], v);
        if (h >= 32 && h <= 42) c6[3] = fmaxf(c6[3], v);
        if (h >= 42 && h <= 53) c6[4] = fmaxf(c6[4], v);
        if (h >= 53)            c6[5] = fmaxf(c6[5], v);
        d8[h >> 3] = fmaxf(d8[h >> 3], v);
    }

    #pragma unroll
    for (int r = 0; r < 3; ++r) band[wv][r][lane] = b3[r];
    #pragma unroll
    for (int r = 0; r < 6; ++r) band[wv][3 + r][lane] = c6[r];
    #pragma unroll
    for (int r = 0; r < 8; ++r) band[wv][9 + r][lane] = d8[r];

    #pragma unroll
    for (int off = 32; off; off >>= 1) a0 = fmaxf(a0, __shfl_xor(a0, off));

    __syncthreads();

    const int isK = (c < CK);
    const int cv = c - CK;

    if (lane == 0) {
        if (isK) keyT[((size_t)b * SP + 0) * CK + c] = f2b(a0);
        else     valueT[((size_t)b * CV + cv) * SP + 0] = f2b(a0);
    }
    {   // s=8: 64 cells
        int i = lane >> 3, j = lane & 7;
        const float* row = band[wv][9 + i];
        float m = row[8 * j];
        #pragma unroll
        for (int k = 1; k < 8; ++k) m = fmaxf(m, row[8 * j + k]);
        int sc = 46 + lane;
        if (isK) keyT[((size_t)b * SP + sc) * CK + c] = f2b(m);
        else     valueT[((size_t)b * CV + cv) * SP + sc] = f2b(m);
    }
    if (lane < 36) {   // s=6
        int i = lane / 6, j = lane - 6 * i;
        int w0 = (j * 64) / 6, w1 = ((j + 1) * 64 + 5) / 6;
        const float* row = band[wv][3 + i];
        float m = NEG;
        for (int k = w0; k < w1; ++k) m = fmaxf(m, row[k]);
        int sc = 10 + lane;
        if (isK) keyT[((size_t)b * SP + sc) * CK + c] = f2b(m);
        else     valueT[((size_t)b * CV + cv) * SP + sc] = f2b(m);
    }
    if (lane < 9) {    // s=3
        int i = lane / 3, j = lane - 3 * i;
        int w0 = (j * 64) / 3, w1 = ((j + 1) * 64 + 2) / 3;
        const float* row = band[wv][i];
        float m = NEG;
        for (int k = w0; k < w1; ++k) m = fmaxf(m, row[k]);
        int sc = 1 + lane;
        if (isK) keyT[((size_t)b * SP + sc) * CK + c] = f2b(m);
        else     valueT[((size_t)b * CV + cv) * SP + sc] = f2b(m);
    }
}

// ---------------------------------------------------------------------------
// FUSED attention: scores MFMA + softmax + P->LDS + PV MFMA.
//   Block = 128 n-rows x one batch. QK^T identical to prior scores kernel;
//   P is written into the (dead) QK A-buffers in stage_tile's swizzled
//   layout (wave wv owns s-tile wv&1), then PV loops 4 cv-tiles of valueT
//   with 2-phase staging into the B-buffers. Yt written directly.
// ---------------------------------------------------------------------------
__global__ __launch_bounds__(256) void attn_fused_kernel(
    const short* __restrict__ qkt, const short* __restrict__ keyT,
    const short* __restrict__ valueT, short* __restrict__ Yt)
{
    __shared__ short As[2][128 * 64];
    __shared__ short Bs[2][128 * 64];
    __shared__ float red[2][2][128];
    const int b  = blockIdx.y;
    const int m0 = blockIdx.x * 128;
    const int tid = threadIdx.x;
    const int lane = tid & 63, wv = tid >> 6;
    const int wm = (wv >> 1) * 64, wn = (wv & 1) * 64;
    const int l15 = lane & 15, l4 = lane >> 4;

    const short* abase = qkt + ((size_t)b * HW + m0) * CK;
    const short* bbase = keyT + (size_t)b * SP * CK;

    f32x4 acc[4][4] = {};
    gemm_loop<4, CK, CK>(abase, bbase, As[0], As[1], Bs[0], Bs[1],
                         tid, wm, wn, l15, l4, acc);

    // ---- fused softmax over s ----
    float pv[4][4][4];   // [m][n][i]
    float rmax[4][4], rsum[4][4];
    #pragma unroll
    for (int m = 0; m < 4; ++m)
        #pragma unroll
        for (int i = 0; i < 4; ++i) {
            float mx = -1e30f;
            #pragma unroll
            for (int n = 0; n < 4; ++n) {
                int s = wn + n * 16 + l15;
                float v = acc[m][n][i] * 0.0625f;
                if (s >= S_) v = -1e30f;
                pv[m][n][i] = v;
                mx = fmaxf(mx, v);
            }
            rmax[m][i] = mx;
        }
    #pragma unroll
    for (int off = 1; off < 16; off <<= 1)
        #pragma unroll
        for (int m = 0; m < 4; ++m)
            #pragma unroll
            for (int i = 0; i < 4; ++i)
                rmax[m][i] = fmaxf(rmax[m][i], __shfl_xor(rmax[m][i], off));
    if (l15 == 0) {
        #pragma unroll
        for (int m = 0; m < 4; ++m)
            #pragma unroll
            for (int i = 0; i < 4; ++i)
                red[0][wv & 1][wm + m * 16 + l4 * 4 + i] = rmax[m][i];
    }
    __syncthreads();
    #pragma unroll
    for (int m = 0; m < 4; ++m)
        #pragma unroll
        for (int i = 0; i < 4; ++i) {
            float gmax = fmaxf(rmax[m][i], red[0][(wv & 1) ^ 1][wm + m * 16 + l4 * 4 + i]);
            float sm = 0.f;
            #pragma unroll
            for (int n = 0; n < 4; ++n) {
                float e = __expf(pv[m][n][i] - gmax);
                pv[m][n][i] = e;
                sm += e;
            }
            rsum[m][i] = sm;
        }
    #pragma unroll
    for (int off = 1; off < 16; off <<= 1)
        #pragma unroll
        for (int m = 0; m < 4; ++m)
            #pragma unroll
            for (int i = 0; i < 4; ++i)
                rsum[m][i] += __shfl_xor(rsum[m][i], off);
    if (l15 == 0) {
        #pragma unroll
        for (int m = 0; m < 4; ++m)
            #pragma unroll
            for (int i = 0; i < 4; ++i)
                red[1][wv & 1][wm + m * 16 + l4 * 4 + i] = rsum[m][i];
    }
    __syncthreads();

    // ---- write P into As[wv&1] in stage_tile's swizzled layout ----
    // value at (row, s): row = wm+m*16+l4*4+i, s = wn+n*16+l15.
    // s-tile = wv&1 (since wn = (wv&1)*64); cs = s&63; unit = cs>>3,
    // swizzled unit' = (cs>>3)^(row&7); element cs&7.
    short* Ps = As[wv & 1];
    #pragma unroll
    for (int m = 0; m < 4; ++m)
        #pragma unroll
        for (int i = 0; i < 4; ++i) {
            int row = wm + m * 16 + l4 * 4 + i;
            float inv = 1.f / (rsum[m][i] + red[1][(wv & 1) ^ 1][row]);
            #pragma unroll
            for (int n = 0; n < 4; ++n) {
                int cs = n * 16 + l15;
                int su = (cs >> 3) ^ (row & 7);
                Ps[row * 64 + su * 8 + (cs & 7)] = f2b(pv[m][n][i] * inv);
            }
        }
    __syncthreads();

    // ---- PV: Yt[n][cv] = sum_s P[n][s] * valueT[cv][s] ----
    const short* vbase = valueT + (size_t)b * CV * SP;
    stage_tile<SP>(vbase, Bs[0], tid, 0);
    __syncthreads();
    f32x4 acc2[4][4] = {};
    #pragma unroll
    for (int step = 0; step < 8; ++step) {
        const int ct = step >> 1, k = step & 1;
        if (step + 1 < 8) {
            const int ct2 = (step + 1) >> 1, k2 = (step + 1) & 1;
            stage_tile<SP>(vbase + (size_t)ct2 * 128 * SP,
                           Bs[(step + 1) & 1], tid, k2 * 64);
        }
        mfma_step(As[k], Bs[step & 1], wm, wn, l15, l4, acc2);
        if (k == 1) {
            #pragma unroll
            for (int m = 0; m < 4; ++m)
                #pragma unroll
                for (int i = 0; i < 4; ++i) {
                    int row = wm + m * 16 + l4 * 4 + i;
                    short* dst = Yt + ((size_t)b * HW + m0 + row) * CV
                               + ct * 128 + wn + l15;
                    #pragma unroll
                    for (int n = 0; n < 4; ++n)
                        dst[n * 16] = f2b(acc2[m][n][i]);
                }
            #pragma unroll
            for (int m = 0; m < 4; ++m)
                #pragma unroll
                for (int n = 0; n < 4; ++n)
                    acc2[m][n] = (f32x4){0.f, 0.f, 0.f, 0.f};
        }
        __syncthreads();
    }
}

// ---------------------------------------------------------------------------
// Launch
// ---------------------------------------------------------------------------
extern "C" void kernel_launch(void* const* d_in, const int* in_sizes, int n_in,
                              void* d_out, int out_size, void* d_ws, size_t ws_size,
                              hipStream_t stream)
{
    const float* x        = (const float*)d_in[0];
    const float* qk_w     = (const float*)d_in[1];
    const float* qk_gamma = (const float*)d_in[2];
    const float* qk_beta  = (const float*)d_in[3];
    const float* qk_mean  = (const float*)d_in[4];
    const float* qk_var   = (const float*)d_in[5];
    const float* v_w      = (const float*)d_in[6];
    const float* v_gamma  = (const float*)d_in[7];
    const float* v_beta   = (const float*)d_in[8];
    const float* v_mean   = (const float*)d_in[9];
    const float* v_var    = (const float*)d_in[10];
    const float* out_w    = (const float*)d_in[11];
    const float* out_gamma= (const float*)d_in[12];
    const float* out_beta = (const float*)d_in[13];
    const float* out_mean = (const float*)d_in[14];
    const float* out_var  = (const float*)d_in[15];

    char* wsb = (char*)d_ws;
    short* xt     = (short*)(wsb);                 // [8][4096][512] bf16 33.5MB
    short* qkt    = xt;                            // aliases xt (dead after gemm<0>)
    short* qkb    = (short*)(wsb + 33554432);      // [8][256][4096] bf16 16.8MB
    short* valb   = (short*)(wsb + 50331648);      // [8][512][4096] bf16 33.5MB
    short* Yt     = valb;                          // aliases valb (dead after pool)
    short* keyT   = (short*)(wsb + 83886080);      // [8][128][256] bf16 0.5MB
    short* valueT = (short*)(wsb + 84410368);      // [8][512][128] bf16 1MB
    short* wqkv   = (short*)(wsb + 93847552);      // [768][512]
    short* wout   = wqkv + 393216;                 // [512][512]

    transpose_x_kernel<<<dim3(HW / 64, CIN / 64, B_), 256, 0, stream>>>(x, xt);
    convert_w_kernel<<<dim3(640), 256, 0, stream>>>(qk_w, v_w, out_w, wqkv);

    gemm_mfma_kernel<0><<<dim3(HW / 128, 6, B_), 256, 0, stream>>>(
        wqkv, xt, qk_gamma, qk_beta, qk_mean, qk_var,
        v_gamma, v_beta, v_mean, v_var,
        nullptr, qkb, valb, nullptr);

    transpose_qk_kernel<<<dim3(HW / 64, CK / 64, B_), 256, 0, stream>>>(qkb, qkt);

    psp_pool_kernel<<<dim3((CK + CV) / 4, B_), 256, 0, stream>>>(qkb, valb, keyT, valueT);

    attn_fused_kernel<<<dim3(HW / 128, B_), 256, 0, stream>>>(qkt, keyT, valueT, Yt);

    gemm_mfma_kernel<1><<<dim3(HW / 128, 4, B_), 256, 0, stream>>>(
        wout, Yt, out_gamma, out_beta, out_mean, out_var,
        nullptr, nullptr, nullptr, nullptr,
        x, nullptr, nullptr, (float*)d_out);
}